// Round 4
// baseline (746.646 us; speedup 1.0000x reference)
//
#include <hip/hip_runtime.h>
#include <math.h>

// ---------------------------------------------------------------------------
// Hyperbolic GCN forward, fully collapsed:
//  - logmap0(proj(expmap0(u))) == u ; bias chain is affine (At,Au per row)
//  - ALL GEMMs on matrix cores via split-bf16 (x = hi + lo, 3 MFMA passes).
//  - Round-4: mfma1(loga1)+mfma2(h1) fused into mfma_dual (128 KB LDS holds
//    BOTH W pairs, 1 block/CU x 8 waves = same 2 waves/SIMD), A1 read once
//    as fp32 + in-register hi/lo split (bit-identical; stage_a eliminated).
//    scan3 folded into consumers (off[row]+bsum[row>>10]); cnt zeroed in
//    split_w3. 13 -> 10 launches.
//  - Round-3 lesson: keep CSR compact (12.8 MB ecv) + separate hist/fill —
//    bucket CSR's sparse 51.2 MB scatter cost +34 us (write-through sectors).
//  - Round-1 lesson: scatter/atomic kernels keep their own massive grids.
//  - LDS XOR swizzle kills the 16-way W-read bank conflict (3.67M -> ~0).
// ---------------------------------------------------------------------------

typedef unsigned short ushort_t;
typedef __attribute__((ext_vector_type(8))) short short8;
typedef __attribute__((ext_vector_type(4))) float f32x4;

__device__ __forceinline__ float wsum(float x){
  x += __shfl_xor(x, 32);
  x += __shfl_xor(x, 16);
  x += __shfl_xor(x, 8);
  x += __shfl_xor(x, 4);
  x += __shfl_xor(x, 2);
  x += __shfl_xor(x, 1);
  return x;
}

__device__ __forceinline__ void get_c(const float* rc, float& K, float& sK){
  float c = log1pf(expf(rc[0])) + 1e-5f;   // softplus(raw_c) + 1e-5
  K  = 1.0f / c;
  sK = sqrtf(K);
}

__device__ __forceinline__ float sinhx_over_x(float x){
  if (x > 1e-3f){
    float e  = __expf(x);
    float em = __builtin_amdgcn_rcpf(e);
    return 0.5f*(e - em) * __builtin_amdgcn_rcpf(x);
  }
  return 1.0f + x*x*(1.0f/6.0f);
}

__device__ __forceinline__ float facosh(float x){   // x >= 1+1e-7
  return __logf(x + sqrtf(fmaxf(fmaf(x, x, -1.0f), 0.0f)));
}

__device__ __forceinline__ ushort_t bf16_rne(float x){
  unsigned int u = __float_as_uint(x);
  u += 0x7fffu + ((u >> 16) & 1u);
  return (ushort_t)(u >> 16);
}
__device__ __forceinline__ float bf2f(ushort_t h){
  return __uint_as_float(((unsigned int)h) << 16);
}
__device__ __forceinline__ unsigned int pack_bf16(float x, float y){
  unsigned int bx = __float_as_uint(x);
  unsigned int by = __float_as_uint(y);
  bx = (bx + 0x7fffu + ((bx >> 16) & 1u)) >> 16;
  by = (by + 0x7fffu + ((by >> 16) & 1u)) & 0xffff0000u;
  return bx | by;
}
__device__ __forceinline__ float bf_lo(unsigned int p){ return __uint_as_float(p << 16); }
__device__ __forceinline__ float bf_hi(unsigned int p){ return __uint_as_float(p & 0xffff0000u); }

// Chain scalars: out_j = At*t_j + Au*u_j == logmap0(mobius_add(exp-chain)).
__device__ __forceinline__ void chain_scalars(float tt, float tu, float uu,
                                              float K, float sK,
                                              float& At, float& Au){
  float xn  = fmaxf(sqrtf(tt), 1e-15f);
  float th  = xn / sK;
  float f   = sinhx_over_x(th);
  float pn2 = f*f*tt;
  float p0  = sqrtf(fmaxf(K + pn2, 1e-7f));
  float S_yu = f * tu;
  float yn  = fmaxf(sqrtf(pn2), 1e-15f);
  float inv_yn = __builtin_amdgcn_rcpf(yn);
  float alpha = S_yu * inv_yn / sK;
  float coef  = alpha * (sK - p0);
  float cy  = coef * inv_yn;
  float cyf = cy * f;
  float pdw  = S_yu - cy*pn2;
  float spsq = uu - 2.f*cy*S_yu + cy*cy*pn2;
  float w0 = pdw / fmaxf(p0, 1e-7f);
  float md = spsq - w0*w0;
  float normu = fminf(sqrtf(fmaxf(md, 1e-7f)), 1e6f);
  float th2 = fmaxf(normu / sK, 1e-15f);
  float e  = __expf(th2);
  float em = __builtin_amdgcn_rcpf(e);
  float ch = 0.5f*(e + em);
  float g  = (th2 > 1e-3f) ? 0.5f*(e - em)*__builtin_amdgcn_rcpf(th2)
                           : 1.0f + th2*th2*(1.0f/6.0f);
  float rn2 = ch*ch*pn2 + 2.f*ch*g*pdw + g*g*spsq;
  float r0 = sqrtf(fmaxf(K + rn2, 1e-7f));
  float ynf = fmaxf(sqrtf(rn2), 1e-15f);
  float thf = fmaxf(r0/sK, 1.f+1e-7f);
  float rf = sK * facosh(thf) * __builtin_amdgcn_rcpf(ynf);
  At = rf*(ch*f - g*cyf);
  Au = rf*g;
}

// ---------- split+transpose all three 128x128 weights + uu3 + cnt zero ------
__global__ __launch_bounds__(256) void split_w3(const float* __restrict__ Lin1,
                                                const float* __restrict__ G1,
                                                const float* __restrict__ G2,
                                                ushort_t* __restrict__ Wb,
                                                const float* __restrict__ b0,
                                                const float* __restrict__ b1,
                                                const float* __restrict__ b2,
                                                float* __restrict__ uu3,
                                                int* __restrict__ cnt, int n){
  int bid = blockIdx.x;           // 0..191
  int which = bid >> 6, b = bid & 63;
  const float* W = (which == 0) ? (Lin1 + 128) : (which == 1) ? (G1 + 128) : G2;
  ushort_t* Whi = Wb + (size_t)which * 2 * 16384;
  ushort_t* Wlo = Whi + 16384;
  int id = b * 256 + threadIdx.x;   // 0..16383
  int k = id >> 7, nn = id & 127;
  float v = W[(size_t)k*128 + nn];
  ushort_t h = bf16_rne(v);
  Whi[(size_t)nn*128 + k] = h;
  Wlo[(size_t)nn*128 + k] = bf16_rne(v - bf2f(h));
  // zero cnt (192*256 = 49152 threads, grid-stride)
  for (int i = bid*256 + threadIdx.x; i < n; i += 192*256) cnt[i] = 0;
  if (bid == 0 && threadIdx.x < 64){
    int lane = threadIdx.x;
    const float* bs[3] = {b0, b1, b2};
    for (int kk = 0; kk < 3; ++kk){
      float x = lane ? bs[kk][2*lane] : 0.0f;
      float y = bs[kk][2*lane+1];
      float s = wsum(x*x + y*y);
      if (lane == 0) uu3[kk] = s;
    }
  }
}

// ---------- FUSED dual MFMA GEMM: loga1 (W1) + h1 (W2) from A1 --------------
// 128 KB LDS = both W pairs; 256 blocks x 512 threads (8 waves, 1 block/CU,
// same 2 waves/SIMD as the 2x(64KB,4-wave) config). A1 read once as fp32
// (stride 129, skip col 0), hi/lo split in-register (bit-identical to the
// old stage_a tables). Per strip: 96 MFMA, two chain epilogues.
__global__ __launch_bounds__(512) void mfma_dual(const float* __restrict__ A1f,
                                                 const ushort_t* __restrict__ W1hi,
                                                 const ushort_t* __restrict__ W1lo,
                                                 const ushort_t* __restrict__ W2hi,
                                                 const ushort_t* __restrict__ W2lo,
                                                 const float* __restrict__ bias1,
                                                 const float* __restrict__ bias2,
                                                 const float* __restrict__ uu3,
                                                 const float* __restrict__ raw_c,
                                                 float* __restrict__ outF,
                                                 unsigned int* __restrict__ outH,
                                                 int n, int nWaves){
  __shared__ ushort_t Wsh[4][128*128];   // 128 KB: W1hi, W1lo, W2hi, W2lo
  int tid = threadIdx.x;
  {
    const uint4* g0 = (const uint4*)W1hi;
    const uint4* g1 = (const uint4*)W1lo;
    const uint4* g2 = (const uint4*)W2hi;
    const uint4* g3 = (const uint4*)W2lo;
    uint4* s0 = (uint4*)Wsh[0]; uint4* s1 = (uint4*)Wsh[1];
    uint4* s2 = (uint4*)Wsh[2]; uint4* s3 = (uint4*)Wsh[3];
    #pragma unroll
    for (int i = 0; i < 4; ++i){
      int idx = tid + 512*i;                 // 0..2047
      int sw = idx ^ ((idx >> 4) & 7);       // uint4-idx swizzle == byte^((n&7)<<4)
      s0[sw] = g0[idx];
      s1[sw] = g1[idx];
      s2[sw] = g2[idx];
      s3[sw] = g3[idx];
    }
  }
  __syncthreads();

  int lane = tid & 63;
  int c = lane & 15, quad = lane >> 4;
  int wid = blockIdx.x * 8 + (tid >> 6);
  int nStrips = (n + 15) >> 4;
  int csw = (c & 7) << 3;                    // ushort-index swizzle for reads

  float K, sK; get_c(raw_c, K, sK);
  float uu1 = uu3[0], uu2 = uu3[1];
  float uv1[8], uv2[8];
  #pragma unroll
  for (int t = 0; t < 8; ++t){
    int col = t*16 + c;
    uv1[t] = (col == 0) ? 0.f : bias1[col];
    uv2[t] = (col == 0) ? 0.f : bias2[col];
  }

  for (int strip = wid; strip < nStrips; strip += nWaves){
    int m0 = strip * 16;
    int ra = m0 + c; if (ra > n - 1) ra = n - 1;
    short8 ahi[4], alo[4];
    {
      const float* ap = A1f + (size_t)ra*129 + 1;
      #pragma unroll
      for (int kc = 0; kc < 4; ++kc){
        int aoff = kc*32 + quad*8;
        #pragma unroll
        for (int j = 0; j < 8; ++j){
          float v = ap[aoff + j];
          ushort_t h = bf16_rne(v);
          ahi[kc][j] = (short)h;
          alo[kc][j] = (short)bf16_rne(v - bf2f(h));
        }
      }
    }

    f32x4 acc1[8], acc2[8];
    #pragma unroll
    for (int t = 0; t < 8; ++t){
      f32x4 z = {0.f, 0.f, 0.f, 0.f};
      acc1[t] = z; acc2[t] = z;
      int wrow = (t*16 + c) * 128;
      #pragma unroll
      for (int kc = 0; kc < 4; ++kc){
        int woff = (wrow + kc*32 + quad*8) ^ csw;
        short8 b1h = *(const short8*)&Wsh[0][woff];
        short8 b1l = *(const short8*)&Wsh[1][woff];
        short8 b2h = *(const short8*)&Wsh[2][woff];
        short8 b2l = *(const short8*)&Wsh[3][woff];
        acc1[t] = __builtin_amdgcn_mfma_f32_16x16x32_bf16(ahi[kc], b1h, acc1[t], 0, 0, 0);
        acc1[t] = __builtin_amdgcn_mfma_f32_16x16x32_bf16(ahi[kc], b1l, acc1[t], 0, 0, 0);
        acc1[t] = __builtin_amdgcn_mfma_f32_16x16x32_bf16(alo[kc], b1h, acc1[t], 0, 0, 0);
        acc2[t] = __builtin_amdgcn_mfma_f32_16x16x32_bf16(ahi[kc], b2h, acc2[t], 0, 0, 0);
        acc2[t] = __builtin_amdgcn_mfma_f32_16x16x32_bf16(ahi[kc], b2l, acc2[t], 0, 0, 0);
        acc2[t] = __builtin_amdgcn_mfma_f32_16x16x32_bf16(alo[kc], b2h, acc2[t], 0, 0, 0);
      }
    }

    if (c == 0){                     // output col 0 = time component, dropped
      f32x4 z = {0.f, 0.f, 0.f, 0.f};
      acc1[0] = z; acc2[0] = z;
    }
    #pragma unroll
    for (int r = 0; r < 4; ++r){
      float tt1 = 0.f, tu1 = 0.f, tt2 = 0.f, tu2 = 0.f;
      #pragma unroll
      for (int t = 0; t < 8; ++t){
        float v1 = acc1[t][r];
        tt1 = fmaf(v1, v1, tt1);
        tu1 = fmaf(v1, uv1[t], tu1);
        float v2 = acc2[t][r];
        tt2 = fmaf(v2, v2, tt2);
        tu2 = fmaf(v2, uv2[t], tu2);
      }
      #pragma unroll
      for (int m = 1; m <= 8; m <<= 1){   // reduce across 16 lanes of the quad
        tt1 += __shfl_xor(tt1, m);
        tu1 += __shfl_xor(tu1, m);
        tt2 += __shfl_xor(tt2, m);
        tu2 += __shfl_xor(tu2, m);
      }
      float At1, Au1; chain_scalars(tt1, tu1, uu1, K, sK, At1, Au1);
      float At2, Au2; chain_scalars(tt2, tu2, uu2, K, sK, At2, Au2);
      int row = m0 + quad*4 + r;
      if (row < n){
        #pragma unroll
        for (int t = 0; t < 8; ++t){
          float o = fmaf(At1, acc1[t][r], Au1*uv1[t]);
          outF[(size_t)row*128 + t*16 + c] = o;
        }
      }
      #pragma unroll
      for (int t = 0; t < 8; ++t){
        float o  = fmaf(At2, acc2[t][r], Au2*uv2[t]);
        float on = __shfl_xor(o, 1);
        if (row < n && !(c & 1))
          outH[(size_t)row*64 + t*8 + (c >> 1)] = pack_bf16(o, on);
      }
    }
  }
}

// ---------- MFMA GEMM (split-bf16 x3) from packed tables (GEMM3) ------------
__global__ __launch_bounds__(256) void mfma_chain(const ushort_t* __restrict__ Ahi,
                                                  const ushort_t* __restrict__ Alo,
                                                  const ushort_t* __restrict__ Whi,
                                                  const ushort_t* __restrict__ Wlo,
                                                  const float* __restrict__ bias,
                                                  const float* __restrict__ uu3, int uuidx,
                                                  const float* __restrict__ raw_c,
                                                  unsigned int* __restrict__ outH,
                                                  int n, int nWaves){
  __shared__ ushort_t Wsh[2][128*128];   // 64 KB: [0]=hi, [1]=lo, swizzled
  int tid = threadIdx.x;
  {
    const uint4* gh = (const uint4*)Whi;
    const uint4* gl = (const uint4*)Wlo;
    uint4* sh = (uint4*)Wsh[0];
    uint4* sl = (uint4*)Wsh[1];
    #pragma unroll
    for (int i = 0; i < 8; ++i){
      int idx = tid + 256*i;
      int sw = idx ^ ((idx >> 4) & 7);
      sh[sw] = gh[idx];
    }
    #pragma unroll
    for (int i = 0; i < 8; ++i){
      int idx = tid + 256*i;
      int sw = idx ^ ((idx >> 4) & 7);
      sl[sw] = gl[idx];
    }
  }
  __syncthreads();

  int lane = tid & 63;
  int c = lane & 15, quad = lane >> 4;
  int wid = blockIdx.x * 4 + (tid >> 6);
  int nStrips = (n + 15) >> 4;
  int csw = (c & 7) << 3;

  float K, sK; get_c(raw_c, K, sK);
  float uu = uu3[uuidx];
  float uv[8];
  #pragma unroll
  for (int t = 0; t < 8; ++t){
    int col = t*16 + c;
    uv[t] = (col == 0) ? 0.f : bias[col];
  }

  for (int strip = wid; strip < nStrips; strip += nWaves){
    int m0 = strip * 16;
    int ra = m0 + c; if (ra > n - 1) ra = n - 1;
    short8 ahi[4], alo[4];
    #pragma unroll
    for (int kc = 0; kc < 4; ++kc){
      size_t aoff = (size_t)ra*128 + kc*32 + quad*8;
      ahi[kc] = *(const short8*)&Ahi[aoff];
      alo[kc] = *(const short8*)&Alo[aoff];
    }

    f32x4 acc[8];
    #pragma unroll
    for (int t = 0; t < 8; ++t){
      f32x4 z = {0.f, 0.f, 0.f, 0.f};
      acc[t] = z;
      int wrow = (t*16 + c) * 128;
      #pragma unroll
      for (int kc = 0; kc < 4; ++kc){
        int woff = (wrow + kc*32 + quad*8) ^ csw;
        short8 bhi = *(const short8*)&Wsh[0][woff];
        short8 blo = *(const short8*)&Wsh[1][woff];
        acc[t] = __builtin_amdgcn_mfma_f32_16x16x32_bf16(ahi[kc], bhi, acc[t], 0, 0, 0);
        acc[t] = __builtin_amdgcn_mfma_f32_16x16x32_bf16(ahi[kc], blo, acc[t], 0, 0, 0);
        acc[t] = __builtin_amdgcn_mfma_f32_16x16x32_bf16(alo[kc], bhi, acc[t], 0, 0, 0);
      }
    }

    if (c == 0){
      f32x4 z = {0.f, 0.f, 0.f, 0.f};
      acc[0] = z;
    }
    #pragma unroll
    for (int r = 0; r < 4; ++r){
      float tt = 0.f, tu = 0.f;
      #pragma unroll
      for (int t = 0; t < 8; ++t){
        float v = acc[t][r];
        tt = fmaf(v, v, tt);
        tu = fmaf(v, uv[t], tu);
      }
      #pragma unroll
      for (int m = 1; m <= 8; m <<= 1){
        tt += __shfl_xor(tt, m);
        tu += __shfl_xor(tu, m);
      }
      float At, Au; chain_scalars(tt, tu, uu, K, sK, At, Au);
      int row = m0 + quad*4 + r;
      #pragma unroll
      for (int t = 0; t < 8; ++t){
        float o  = fmaf(At, acc[t][r], Au*uv[t]);
        float on = __shfl_xor(o, 1);
        if (row < n && !(c & 1))
          outH[(size_t)row*64 + t*8 + (c >> 1)] = pack_bf16(o, on);
      }
    }
  }
}

// --------------------------- CSR build -------------------------------------
__global__ __launch_bounds__(256) void hist_k(const int* __restrict__ rows,
                                              int* __restrict__ cnt,
                                              int* __restrict__ rnk, int e){
  int base = (blockIdx.x * 256 + threadIdx.x) * 4;
  if (base + 3 < e){
    int4 r = *(const int4*)&rows[base];
    int k0 = atomicAdd(&cnt[r.x], 1);
    int k1 = atomicAdd(&cnt[r.y], 1);
    int k2 = atomicAdd(&cnt[r.z], 1);
    int k3 = atomicAdd(&cnt[r.w], 1);
    *(int4*)&rnk[base] = make_int4(k0, k1, k2, k3);
  } else {
    for (int i = base; i < e; ++i) rnk[i] = atomicAdd(&cnt[rows[i]], 1);
  }
}

#define SCAN_ITEMS 4
__global__ __launch_bounds__(256) void scan1(const int* __restrict__ cnt,
                                             int* __restrict__ off,
                                             int* __restrict__ bsum, int n){
  __shared__ int sh[256];
  int tid = threadIdx.x;
  int base = blockIdx.x * 256 * SCAN_ITEMS + tid * SCAN_ITEMS;
  int v[SCAN_ITEMS]; int s = 0;
  #pragma unroll
  for (int i = 0; i < SCAN_ITEMS; ++i){ int idx = base+i; v[i] = (idx < n) ? cnt[idx] : 0; s += v[i]; }
  sh[tid] = s; __syncthreads();
  for (int o = 1; o < 256; o <<= 1){
    int t = (tid >= o) ? sh[tid - o] : 0; __syncthreads();
    sh[tid] += t; __syncthreads();
  }
  int excl = sh[tid] - s;
  if (tid == 255) bsum[blockIdx.x] = sh[tid];
  int run = excl;
  #pragma unroll
  for (int i = 0; i < SCAN_ITEMS; ++i){ int idx = base+i; if (idx < n) off[idx] = run; run += v[i]; }
}

// parallel exclusive scan of block sums (G <= 256; G = ceil(N/1024) = 98)
__global__ __launch_bounds__(256) void scan2(int* __restrict__ bsum, int G){
  __shared__ int sh[256];
  int t = threadIdx.x;
  int v = (t < G) ? bsum[t] : 0;
  sh[t] = v; __syncthreads();
  for (int o = 1; o < 256; o <<= 1){
    int x = (t >= o) ? sh[t - o] : 0; __syncthreads();
    sh[t] += x; __syncthreads();
  }
  if (t < G) bsum[t] = sh[t] - v;
}

// fill with consumer-side bsum add (scan3 eliminated)
__global__ __launch_bounds__(256) void fill_k(const int* __restrict__ rows,
                                              const int* __restrict__ cols,
                                              const float* __restrict__ vals,
                                              const int* __restrict__ off,
                                              const int* __restrict__ bsum,
                                              const int* __restrict__ rnk,
                                              int2* __restrict__ ecv, int e){
  int base = (blockIdx.x * 256 + threadIdx.x) * 4;
  if (base + 3 < e){
    int4   r = *(const int4*)&rows[base];
    int4   q = *(const int4*)&rnk[base];
    int4   c = *(const int4*)&cols[base];
    float4 v = *(const float4*)&vals[base];
    int o0 = off[r.x] + bsum[r.x >> 10];
    int o1 = off[r.y] + bsum[r.y >> 10];
    int o2 = off[r.z] + bsum[r.z >> 10];
    int o3 = off[r.w] + bsum[r.w >> 10];
    ecv[o0 + q.x] = make_int2(c.x, __float_as_int(v.x));
    ecv[o1 + q.y] = make_int2(c.y, __float_as_int(v.y));
    ecv[o2 + q.z] = make_int2(c.z, __float_as_int(v.z));
    ecv[o3 + q.w] = make_int2(c.w, __float_as_int(v.w));
  } else {
    for (int i = base; i < e; ++i)
      ecv[off[rows[i]] + bsum[rows[i] >> 10] + rnk[i]] = make_int2(cols[i], __float_as_int(vals[i]));
  }
}

// --------------------------- seg-sum (bf16 table, int2 edges) ---------------
__device__ __forceinline__ float2 seg_gather_bf16(const unsigned int* __restrict__ h,
                                                  const int* __restrict__ off,
                                                  const int* __restrict__ bsum,
                                                  const int* __restrict__ cnt,
                                                  const int2* __restrict__ ecv,
                                                  int row, int lane){
  float ax = 0.f, ay = 0.f, bx = 0.f, by = 0.f;
  int st = off[row] + bsum[row >> 10], deg = cnt[row];
  const unsigned int* __restrict__ hb = h + lane;   // row stride = 64 uints
  for (int b = 0; b < deg; b += 64){
    int k = b + lane;
    int cc = 0; float vv = 0.f;
    if (k < deg){ int2 e = ecv[st+k]; cc = e.x; vv = __int_as_float(e.y); }
    int m = min(64, deg - b);
    for (int j = 0; j < m; j += 8){
      int   c0=__shfl(cc,j+0), c1=__shfl(cc,j+1), c2=__shfl(cc,j+2), c3=__shfl(cc,j+3);
      int   c4=__shfl(cc,j+4), c5=__shfl(cc,j+5), c6=__shfl(cc,j+6), c7=__shfl(cc,j+7);
      float v0=__shfl(vv,j+0), v1=__shfl(vv,j+1), v2=__shfl(vv,j+2), v3=__shfl(vv,j+3);
      float v4=__shfl(vv,j+4), v5=__shfl(vv,j+5), v6=__shfl(vv,j+6), v7=__shfl(vv,j+7);
      unsigned int p0 = hb[(size_t)c0*64];
      unsigned int p1 = hb[(size_t)c1*64];
      unsigned int p2 = hb[(size_t)c2*64];
      unsigned int p3 = hb[(size_t)c3*64];
      unsigned int p4 = hb[(size_t)c4*64];
      unsigned int p5 = hb[(size_t)c5*64];
      unsigned int p6 = hb[(size_t)c6*64];
      unsigned int p7 = hb[(size_t)c7*64];
      ax = fmaf(v0, bf_lo(p0), ax); ay = fmaf(v0, bf_hi(p0), ay);
      bx = fmaf(v1, bf_lo(p1), bx); by = fmaf(v1, bf_hi(p1), by);
      ax = fmaf(v2, bf_lo(p2), ax); ay = fmaf(v2, bf_hi(p2), ay);
      bx = fmaf(v3, bf_lo(p3), bx); by = fmaf(v3, bf_hi(p3), by);
      ax = fmaf(v4, bf_lo(p4), ax); ay = fmaf(v4, bf_hi(p4), ay);
      bx = fmaf(v5, bf_lo(p5), bx); by = fmaf(v5, bf_hi(p5), by);
      ax = fmaf(v6, bf_lo(p6), ax); ay = fmaf(v6, bf_hi(p6), ay);
      bx = fmaf(v7, bf_lo(p7), bx); by = fmaf(v7, bf_hi(p7), by);
    }
  }
  return make_float2(ax + bx, ay + by);
}

// ------ seg_x1: Lx1 = (1-n)*segsum(h1) + n*loga1 -> bf16 hi/lo split --------
__global__ __launch_bounds__(256) void seg_x1(const unsigned int* __restrict__ h1,
                                              const int* __restrict__ off,
                                              const int* __restrict__ bsum,
                                              const int* __restrict__ cnt,
                                              const int2* __restrict__ ecv,
                                              const float* __restrict__ loga1,
                                              const float* __restrict__ nparam,
                                              unsigned int* __restrict__ X1hi,
                                              unsigned int* __restrict__ X1lo, int n){
  int row  = (int)((blockIdx.x * blockDim.x + threadIdx.x) >> 6);
  int lane = threadIdx.x & 63;
  if (row >= n) return;
  float2 acc = seg_gather_bf16(h1, off, bsum, cnt, ecv, row, lane);
  float nv = nparam[row];
  float2 la1 = *(const float2*)&loga1[(size_t)row*128 + 2*lane];
  float ox = (1.f-nv)*acc.x + nv*la1.x;
  float oy = (1.f-nv)*acc.y + nv*la1.y;
  unsigned int hp = pack_bf16(ox, oy);
  X1hi[(size_t)row*64 + lane] = hp;
  X1lo[(size_t)row*64 + lane] = pack_bf16(ox - bf_lo(hp), oy - bf_hi(hp));
}

// ------------------- seg_x2: Lx2 = segsum(h2)  (packed bf16 out) ------------
__global__ __launch_bounds__(256) void seg_x2(const unsigned int* __restrict__ h2,
                                              const int* __restrict__ off,
                                              const int* __restrict__ bsum,
                                              const int* __restrict__ cnt,
                                              const int2* __restrict__ ecv,
                                              unsigned int* __restrict__ Lx2p, int n){
  int row  = (int)((blockIdx.x * blockDim.x + threadIdx.x) >> 6);
  int lane = threadIdx.x & 63;
  if (row >= n) return;
  float2 acc = seg_gather_bf16(h2, off, bsum, cnt, ecv, row, lane);
  Lx2p[(size_t)row*64 + lane] = pack_bf16(acc.x, acc.y);
}

// --------------------------- batch head -------------------------------------
// d<64: s2 gather from packed-bf16 Lx2; d>=64: s3 gather from fp32 loga1.
__global__ __launch_bounds__(128) void batch_head(const unsigned int* __restrict__ Lx2p,
                                                  const float* __restrict__ loga1,
                                                  const int* __restrict__ bidx,
                                                  const float* __restrict__ weight,
                                                  const float* __restrict__ weight2,
                                                  const float* __restrict__ c1w,
                                                  const float* __restrict__ c1b,
                                                  const float* __restrict__ c2w,
                                                  const float* __restrict__ c2b,
                                                  const float* __restrict__ cls,
                                                  const float* __restrict__ clsb,
                                                  float* __restrict__ out, int Bn){
  __shared__ float sg2[128], sg3[128], ssel[100], spre[5];
  __shared__ int sbi[50];
  __shared__ float sc1[50], sc2[50];
  int b = blockIdx.x, d = threadIdx.x;
  const int* bi = bidx + (size_t)b * 50;
  if (d < 50){ sbi[d] = bi[d]; sc1[d] = c1w[d]; sc2[d] = c2w[d]; }
  __syncthreads();
  int lane = d & 63;
  bool lo = d < 64;
  float gx = 0.f, gy = 0.f;
  if (lo){
    const unsigned int* __restrict__ tp = Lx2p + lane;   // row stride 64 uints
    #pragma unroll
    for (int l = 0; l < 50; l += 5){
      int i0 = sbi[l+0], i1 = sbi[l+1], i2 = sbi[l+2], i3 = sbi[l+3], i4 = sbi[l+4];
      unsigned int p0 = tp[(size_t)i0*64];
      unsigned int p1 = tp[(size_t)i1*64];
      unsigned int p2 = tp[(size_t)i2*64];
      unsigned int p3 = tp[(size_t)i3*64];
      unsigned int p4 = tp[(size_t)i4*64];
      float w0 = sc1[l+0], w1 = sc1[l+1], w2 = sc1[l+2], w3 = sc1[l+3], w4 = sc1[l+4];
      gx = fmaf(w0, bf_lo(p0), gx); gy = fmaf(w0, bf_hi(p0), gy);
      gx = fmaf(w1, bf_lo(p1), gx); gy = fmaf(w1, bf_hi(p1), gy);
      gx = fmaf(w2, bf_lo(p2), gx); gy = fmaf(w2, bf_hi(p2), gy);
      gx = fmaf(w3, bf_lo(p3), gx); gy = fmaf(w3, bf_hi(p3), gy);
      gx = fmaf(w4, bf_lo(p4), gx); gy = fmaf(w4, bf_hi(p4), gy);
    }
    sg2[2*lane] = gx; sg2[2*lane+1] = gy;
  } else {
    const float2* __restrict__ t2 = (const float2*)loga1 + lane;  // row stride 64
    #pragma unroll
    for (int l = 0; l < 50; l += 5){
      int i0 = sbi[l+0], i1 = sbi[l+1], i2 = sbi[l+2], i3 = sbi[l+3], i4 = sbi[l+4];
      float2 p0 = t2[(size_t)i0*64];
      float2 p1 = t2[(size_t)i1*64];
      float2 p2 = t2[(size_t)i2*64];
      float2 p3 = t2[(size_t)i3*64];
      float2 p4 = t2[(size_t)i4*64];
      float w0 = sc2[l+0], w1 = sc2[l+1], w2 = sc2[l+2], w3 = sc2[l+3], w4 = sc2[l+4];
      gx = fmaf(w0, p0.x, gx); gy = fmaf(w0, p0.y, gy);
      gx = fmaf(w1, p1.x, gx); gy = fmaf(w1, p1.y, gy);
      gx = fmaf(w2, p2.x, gx); gy = fmaf(w2, p2.y, gy);
      gx = fmaf(w3, p3.x, gx); gy = fmaf(w3, p3.y, gy);
      gx = fmaf(w4, p4.x, gx); gy = fmaf(w4, p4.y, gy);
    }
    sg3[2*lane] = gx; sg3[2*lane+1] = gy;
  }
  __syncthreads();
  if (d < 50){
    float s = 0.f;
    for (int k = 0; k < 128; ++k) s = fmaf(sg2[k], weight[k*50 + d], s);
    s += c1b[0];
    ssel[d] = s;
    out[(size_t)Bn + (size_t)b*100 + d] = s;
  } else if (d >= 64 && d < 114){
    int t = d - 64;
    float s = 0.f;
    for (int k = 0; k < 128; ++k) s = fmaf(sg3[k], weight2[k*50 + t], s);
    s += c2b[0];
    ssel[50 + t] = s;
    out[(size_t)Bn + (size_t)b*100 + 50 + t] = s;
  }
  __syncthreads();
  if (d < 5){
    float s = clsb[d];
    for (int j = 0; j < 100; ++j) s = fmaf(ssel[j], cls[j*5 + d], s);
    spre[d] = s;
  }
  __syncthreads();
  if (d == 0){
    int best = 0; float bv = spre[0];
    #pragma unroll
    for (int k = 1; k < 5; ++k) if (spre[k] > bv){ bv = spre[k]; best = k; }
    out[b] = (float)best;
  }
}

// ---------------------------------------------------------------------------
extern "C" void kernel_launch(void* const* d_in, const int* in_sizes, int n_in,
                              void* d_out, int out_size, void* d_ws, size_t ws_size,
                              hipStream_t stream) {
  const float* A1     = (const float*)d_in[0];
  const int*   rows   = (const int*)  d_in[1];
  const int*   cols   = (const int*)  d_in[2];
  const float* vals   = (const float*)d_in[3];
  const int*   bidx   = (const int*)  d_in[4];
  const float* raw_c  = (const float*)d_in[5];
  const float* nparam = (const float*)d_in[6];
  const float* Lin1   = (const float*)d_in[7];
  const float* Lin1_b = (const float*)d_in[8];
  const float* gc1_w  = (const float*)d_in[9];
  const float* gc1_b  = (const float*)d_in[10];
  const float* gc2_w  = (const float*)d_in[11];
  const float* gc2_b  = (const float*)d_in[12];
  const float* weight = (const float*)d_in[13];
  const float* weight2= (const float*)d_in[14];
  const float* c1w    = (const float*)d_in[15];
  const float* c1b    = (const float*)d_in[16];
  const float* c2w    = (const float*)d_in[17];
  const float* c2b    = (const float*)d_in[18];
  const float* cls    = (const float*)d_in[19];
  const float* clsb   = (const float*)d_in[20];

  int N  = in_sizes[0] / 129;
  int E  = in_sizes[1];
  int Bn = in_sizes[4] / 50;
  size_t NF = (size_t)N * 128;

  // workspace layout (round-2 offsets; region 0 now only hosts Lx2p alias)
  unsigned int* Lx2p = (unsigned int*)d_ws;     // N*64 uints (25.6 MB region 0)
  float*    S3  = (float*)((char*)d_ws + 4*NF); // loga1 fp32, 4NF B
  unsigned int* Hb   = (unsigned int*)(S3 + NF);  // h1/h2 bf16, NF/2 uints
  unsigned int* X1hi = Hb + NF/2;               // Lx1 hi
  unsigned int* X1lo = X1hi + NF/2;             // Lx1 lo
  ushort_t* Wb = (ushort_t*)(X1lo + NF/2);      // 6 x 16384 ushorts
  ushort_t* W1h = Wb,           *W1l = Wb + 16384;
  ushort_t* W2h = Wb + 2*16384, *W2l = Wb + 3*16384;
  ushort_t* W3h = Wb + 4*16384, *W3l = Wb + 5*16384;
  int* cnt    = (int*)(Wb + 6*16384);
  int* off    = cnt + N;
  int* rnk    = off + N;
  int* bsum   = rnk + E;
  int2* ecv   = (int2*)(bsum + 4096);
  float* uu3  = (float*)(ecv + E);

  int rowBlocks  = (N + 3) / 4;
  int G = (N + 256*SCAN_ITEMS - 1) / (256*SCAN_ITEMS);
  int eBlocks4 = (E/4 + 255) / 256 + 1;

  split_w3<<<192, 256, 0, stream>>>(Lin1, gc1_w, gc2_w, Wb,
                                    Lin1_b, gc1_b, gc2_b, uu3, cnt, N);

  hist_k<<<eBlocks4, 256, 0, stream>>>(rows, cnt, rnk, E);
  scan1<<<G, 256, 0, stream>>>(cnt, off, bsum, N);
  scan2<<<1, 256, 0, stream>>>(bsum, G);
  fill_k<<<eBlocks4, 256, 0, stream>>>(rows, cols, vals, off, bsum, rnk, ecv, E);

  // loga1 (fp32 -> S3) + h1 (packed -> Hb) fused; A1 read once
  mfma_dual<<<256, 512, 0, stream>>>(A1, W1h, W1l, W2h, W2l,
                                     Lin1_b, gc1_b, uu3, raw_c,
                                     S3, Hb, N, 256*8);
  seg_x1<<<rowBlocks, 256, 0, stream>>>(Hb, off, bsum, cnt, ecv, S3, nparam,
                                        X1hi, X1lo, N);
  // h2 = chain(Lx1@gc2_w, gc2_b) -> Hb (bf16); X1 packed tables
  mfma_chain<<<512, 256, 0, stream>>>((const ushort_t*)X1hi, (const ushort_t*)X1lo,
                                      W3h, W3l, gc2_b, uu3, 2, raw_c,
                                      Hb, N, 512*4);
  seg_x2<<<rowBlocks, 256, 0, stream>>>(Hb, off, bsum, cnt, ecv, Lx2p, N);
  batch_head<<<Bn, 128, 0, stream>>>(Lx2p, S3, bidx, weight, weight2, c1w, c1b,
                                     c2w, c2b, cls, clsb, (float*)d_out, Bn);
}

// Round 5
// 732.386 us; speedup vs baseline: 1.0195x; 1.0195x over previous
//
#include <hip/hip_runtime.h>
#include <math.h>

// ---------------------------------------------------------------------------
// Hyperbolic GCN forward, fully collapsed:
//  - logmap0(proj(expmap0(u))) == u ; bias chain is affine (At,Au per row)
//  - ALL GEMMs on matrix cores via split-bf16 (x = hi + lo, 3 MFMA passes).
//  - Round-5: mfma1+mfma2 fused into mfma12 with SEQUENTIAL accumulators
//    (round-4 lesson: simultaneous acc1+acc2 liveness -> 128-VGPR cap ->
//    spill-to-scratch -> 580 MB of extra HBM traffic, 300us. Sequential
//    passes keep peak pressure == single-chain kernel; __launch_bounds__
//    (512,2) budgets 256 VGPRs so no spill-to-fit). A tables read ONCE.
//    stage_a+split_w3 merged into one prep kernel (block-role split).
//  - Round-3 lesson: keep CSR compact + separate hist/fill passes.
//  - Round-1 lesson: scatter/atomic kernels keep their own massive grids.
//  - LDS XOR swizzle kills the 16-way W-read bank conflict (3.67M -> ~0).
// ---------------------------------------------------------------------------

typedef unsigned short ushort_t;
typedef __attribute__((ext_vector_type(8))) short short8;
typedef __attribute__((ext_vector_type(4))) float f32x4;
typedef __attribute__((ext_vector_type(4))) unsigned short u16x4;

__device__ __forceinline__ float wsum(float x){
  x += __shfl_xor(x, 32);
  x += __shfl_xor(x, 16);
  x += __shfl_xor(x, 8);
  x += __shfl_xor(x, 4);
  x += __shfl_xor(x, 2);
  x += __shfl_xor(x, 1);
  return x;
}

__device__ __forceinline__ void get_c(const float* rc, float& K, float& sK){
  float c = log1pf(expf(rc[0])) + 1e-5f;   // softplus(raw_c) + 1e-5
  K  = 1.0f / c;
  sK = sqrtf(K);
}

__device__ __forceinline__ float sinhx_over_x(float x){
  if (x > 1e-3f){
    float e  = __expf(x);
    float em = __builtin_amdgcn_rcpf(e);
    return 0.5f*(e - em) * __builtin_amdgcn_rcpf(x);
  }
  return 1.0f + x*x*(1.0f/6.0f);
}

__device__ __forceinline__ float facosh(float x){   // x >= 1+1e-7
  return __logf(x + sqrtf(fmaxf(fmaf(x, x, -1.0f), 0.0f)));
}

__device__ __forceinline__ ushort_t bf16_rne(float x){
  unsigned int u = __float_as_uint(x);
  u += 0x7fffu + ((u >> 16) & 1u);
  return (ushort_t)(u >> 16);
}
__device__ __forceinline__ float bf2f(ushort_t h){
  return __uint_as_float(((unsigned int)h) << 16);
}
__device__ __forceinline__ unsigned int pack_bf16(float x, float y){
  unsigned int bx = __float_as_uint(x);
  unsigned int by = __float_as_uint(y);
  bx = (bx + 0x7fffu + ((bx >> 16) & 1u)) >> 16;
  by = (by + 0x7fffu + ((by >> 16) & 1u)) & 0xffff0000u;
  return bx | by;
}
__device__ __forceinline__ float bf_lo(unsigned int p){ return __uint_as_float(p << 16); }
__device__ __forceinline__ float bf_hi(unsigned int p){ return __uint_as_float(p & 0xffff0000u); }

// Chain scalars: out_j = At*t_j + Au*u_j == logmap0(mobius_add(exp-chain)).
__device__ __forceinline__ void chain_scalars(float tt, float tu, float uu,
                                              float K, float sK,
                                              float& At, float& Au){
  float xn  = fmaxf(sqrtf(tt), 1e-15f);
  float th  = xn / sK;
  float f   = sinhx_over_x(th);
  float pn2 = f*f*tt;
  float p0  = sqrtf(fmaxf(K + pn2, 1e-7f));
  float S_yu = f * tu;
  float yn  = fmaxf(sqrtf(pn2), 1e-15f);
  float inv_yn = __builtin_amdgcn_rcpf(yn);
  float alpha = S_yu * inv_yn / sK;
  float coef  = alpha * (sK - p0);
  float cy  = coef * inv_yn;
  float cyf = cy * f;
  float pdw  = S_yu - cy*pn2;
  float spsq = uu - 2.f*cy*S_yu + cy*cy*pn2;
  float w0 = pdw / fmaxf(p0, 1e-7f);
  float md = spsq - w0*w0;
  float normu = fminf(sqrtf(fmaxf(md, 1e-7f)), 1e6f);
  float th2 = fmaxf(normu / sK, 1e-15f);
  float e  = __expf(th2);
  float em = __builtin_amdgcn_rcpf(e);
  float ch = 0.5f*(e + em);
  float g  = (th2 > 1e-3f) ? 0.5f*(e - em)*__builtin_amdgcn_rcpf(th2)
                           : 1.0f + th2*th2*(1.0f/6.0f);
  float rn2 = ch*ch*pn2 + 2.f*ch*g*pdw + g*g*spsq;
  float r0 = sqrtf(fmaxf(K + rn2, 1e-7f));
  float ynf = fmaxf(sqrtf(rn2), 1e-15f);
  float thf = fmaxf(r0/sK, 1.f+1e-7f);
  float rf = sK * facosh(thf) * __builtin_amdgcn_rcpf(ynf);
  At = rf*(ch*f - g*cyf);
  Au = rf*g;
}

// ---------- prep: stage_a (blocks < sBlocks) + split_w3 (blocks >= sBlocks) --
__global__ __launch_bounds__(256) void prep(const float* __restrict__ A1,
                                            ushort_t* __restrict__ Lhi,
                                            ushort_t* __restrict__ Llo,
                                            int* __restrict__ cnt,
                                            const float* __restrict__ Lin1,
                                            const float* __restrict__ G1,
                                            const float* __restrict__ G2,
                                            ushort_t* __restrict__ Wb,
                                            const float* __restrict__ b0,
                                            const float* __restrict__ b1,
                                            const float* __restrict__ b2,
                                            float* __restrict__ uu3,
                                            int n, int sBlocks){
  int bid = blockIdx.x;
  if (bid < sBlocks){
    size_t i4 = (size_t)bid * 256 + threadIdx.x;
    size_t tot4 = (size_t)n * 32;
    if (i4 < tot4){
      size_t row = i4 >> 5; int j0 = (int)(i4 & 31) * 4;
      const float* s = A1 + row*129 + 1 + j0;
      float v0 = s[0], v1 = s[1], v2 = s[2], v3 = s[3];
      ushort_t h0 = bf16_rne(v0), h1 = bf16_rne(v1), h2 = bf16_rne(v2), h3 = bf16_rne(v3);
      u16x4 hh = {h0, h1, h2, h3};
      u16x4 ll = {bf16_rne(v0 - bf2f(h0)), bf16_rne(v1 - bf2f(h1)),
                  bf16_rne(v2 - bf2f(h2)), bf16_rne(v3 - bf2f(h3))};
      *(u16x4*)&Lhi[i4*4] = hh;
      *(u16x4*)&Llo[i4*4] = ll;
    }
    if (i4 < (size_t)n) cnt[i4] = 0;
    if (bid == 0 && threadIdx.x < 64){
      int lane = threadIdx.x;
      const float* bs[3] = {b0, b1, b2};
      for (int k = 0; k < 3; ++k){
        float x = lane ? bs[k][2*lane] : 0.0f;
        float y = bs[k][2*lane+1];
        float s = wsum(x*x + y*y);
        if (lane == 0) uu3[k] = s;
      }
    }
  } else {
    int wb = bid - sBlocks;          // 0..191
    int which = wb >> 6, b = wb & 63;
    const float* W = (which == 0) ? (Lin1 + 128) : (which == 1) ? (G1 + 128) : G2;
    ushort_t* Whi = Wb + (size_t)which * 2 * 16384;
    ushort_t* Wlo = Whi + 16384;
    int id = b * 256 + threadIdx.x;   // 0..16383
    int k = id >> 7, nn = id & 127;
    float v = W[(size_t)k*128 + nn];
    ushort_t h = bf16_rne(v);
    Whi[(size_t)nn*128 + k] = h;
    Wlo[(size_t)nn*128 + k] = bf16_rne(v - bf2f(h));
  }
}

// ---------- FUSED GEMM1+GEMM2: loga1 (W1 -> fp32) + h1 (W2 -> packed) -------
// A tables read ONCE per strip; the two accumulator sets are computed in
// SEQUENTIAL passes (acc dies before pass 2 starts) so peak VGPR pressure
// equals the single-chain kernel. 128 KB LDS (4 W buffers, XOR-swizzled);
// 256 blocks x 512 threads = 8 waves, 1 block/CU, 2 waves/SIMD.
// __launch_bounds__(512,2): VGPR budget 256 -> no spill-to-fit (round-4 bug).
__global__ __launch_bounds__(512, 2) void mfma12(const ushort_t* __restrict__ Ahi,
                                                 const ushort_t* __restrict__ Alo,
                                                 const ushort_t* __restrict__ Wb,
                                                 const float* __restrict__ bias1,
                                                 const float* __restrict__ bias2,
                                                 const float* __restrict__ uu3,
                                                 const float* __restrict__ raw_c,
                                                 float* __restrict__ outF,
                                                 unsigned int* __restrict__ outH,
                                                 int n, int nWaves){
  __shared__ ushort_t Wsh[4][128*128];   // 128 KB: W1hi, W1lo, W2hi, W2lo
  int tid = threadIdx.x;
  {
    const uint4* g = (const uint4*)Wb;   // 4 buffers x 2048 uint4
    uint4* s = (uint4*)Wsh[0];
    #pragma unroll
    for (int i = 0; i < 16; ++i){
      int idx = tid + 512*i;                 // 0..8191
      int within = idx & 2047;
      int sw = (idx & ~2047) | (within ^ ((within >> 4) & 7));
      s[sw] = g[idx];
    }
  }
  __syncthreads();

  int lane = tid & 63;
  int c = lane & 15, quad = lane >> 4;
  int wid = blockIdx.x * 8 + (tid >> 6);
  int nStrips = (n + 15) >> 4;
  int csw = (c & 7) << 3;                    // ushort-index swizzle for reads

  float K, sK; get_c(raw_c, K, sK);
  float uu1 = uu3[0], uu2 = uu3[1];
  float uv1[8], uv2[8];
  #pragma unroll
  for (int t = 0; t < 8; ++t){
    int col = t*16 + c;
    uv1[t] = (col == 0) ? 0.f : bias1[col];
    uv2[t] = (col == 0) ? 0.f : bias2[col];
  }

  for (int strip = wid; strip < nStrips; strip += nWaves){
    int m0 = strip * 16;
    int ra = m0 + c; if (ra > n - 1) ra = n - 1;
    short8 ahi[4], alo[4];
    #pragma unroll
    for (int kc = 0; kc < 4; ++kc){
      size_t aoff = (size_t)ra*128 + kc*32 + quad*8;
      ahi[kc] = *(const short8*)&Ahi[aoff];
      alo[kc] = *(const short8*)&Alo[aoff];
    }

    // ----------------- pass 1: W1 -> loga1 (fp32) -----------------
    {
      f32x4 acc[8];
      #pragma unroll
      for (int t = 0; t < 8; ++t){
        f32x4 z = {0.f, 0.f, 0.f, 0.f};
        acc[t] = z;
        int wrow = (t*16 + c) * 128;
        #pragma unroll
        for (int kc = 0; kc < 4; ++kc){
          int woff = (wrow + kc*32 + quad*8) ^ csw;
          short8 bhi = *(const short8*)&Wsh[0][woff];
          short8 blo = *(const short8*)&Wsh[1][woff];
          acc[t] = __builtin_amdgcn_mfma_f32_16x16x32_bf16(ahi[kc], bhi, acc[t], 0, 0, 0);
          acc[t] = __builtin_amdgcn_mfma_f32_16x16x32_bf16(ahi[kc], blo, acc[t], 0, 0, 0);
          acc[t] = __builtin_amdgcn_mfma_f32_16x16x32_bf16(alo[kc], bhi, acc[t], 0, 0, 0);
        }
      }
      if (c == 0){ f32x4 z = {0.f,0.f,0.f,0.f}; acc[0] = z; }
      #pragma unroll
      for (int r = 0; r < 4; ++r){
        float tt = 0.f, tu = 0.f;
        #pragma unroll
        for (int t = 0; t < 8; ++t){
          float v = acc[t][r];
          tt = fmaf(v, v, tt);
          tu = fmaf(v, uv1[t], tu);
        }
        #pragma unroll
        for (int m = 1; m <= 8; m <<= 1){
          tt += __shfl_xor(tt, m);
          tu += __shfl_xor(tu, m);
        }
        float At, Au; chain_scalars(tt, tu, uu1, K, sK, At, Au);
        int row = m0 + quad*4 + r;
        if (row < n){
          #pragma unroll
          for (int t = 0; t < 8; ++t){
            float o = fmaf(At, acc[t][r], Au*uv1[t]);
            outF[(size_t)row*128 + t*16 + c] = o;
          }
        }
      }
    }

    // ----------------- pass 2: W2 -> h1 (packed bf16) -----------------
    {
      f32x4 acc[8];
      #pragma unroll
      for (int t = 0; t < 8; ++t){
        f32x4 z = {0.f, 0.f, 0.f, 0.f};
        acc[t] = z;
        int wrow = (t*16 + c) * 128;
        #pragma unroll
        for (int kc = 0; kc < 4; ++kc){
          int woff = (wrow + kc*32 + quad*8) ^ csw;
          short8 bhi = *(const short8*)&Wsh[2][woff];
          short8 blo = *(const short8*)&Wsh[3][woff];
          acc[t] = __builtin_amdgcn_mfma_f32_16x16x32_bf16(ahi[kc], bhi, acc[t], 0, 0, 0);
          acc[t] = __builtin_amdgcn_mfma_f32_16x16x32_bf16(ahi[kc], blo, acc[t], 0, 0, 0);
          acc[t] = __builtin_amdgcn_mfma_f32_16x16x32_bf16(alo[kc], bhi, acc[t], 0, 0, 0);
        }
      }
      if (c == 0){ f32x4 z = {0.f,0.f,0.f,0.f}; acc[0] = z; }
      #pragma unroll
      for (int r = 0; r < 4; ++r){
        float tt = 0.f, tu = 0.f;
        #pragma unroll
        for (int t = 0; t < 8; ++t){
          float v = acc[t][r];
          tt = fmaf(v, v, tt);
          tu = fmaf(v, uv2[t], tu);
        }
        #pragma unroll
        for (int m = 1; m <= 8; m <<= 1){
          tt += __shfl_xor(tt, m);
          tu += __shfl_xor(tu, m);
        }
        float At, Au; chain_scalars(tt, tu, uu2, K, sK, At, Au);
        int row = m0 + quad*4 + r;
        #pragma unroll
        for (int t = 0; t < 8; ++t){
          float o  = fmaf(At, acc[t][r], Au*uv2[t]);
          float on = __shfl_xor(o, 1);
          if (row < n && !(c & 1))
            outH[(size_t)row*64 + t*8 + (c >> 1)] = pack_bf16(o, on);
        }
      }
    }
  }
}

// ---------- GEMM3 (split-bf16 x3) from packed tables, packed out ------------
__global__ __launch_bounds__(256) void mfma_chain(const ushort_t* __restrict__ Ahi,
                                                  const ushort_t* __restrict__ Alo,
                                                  const ushort_t* __restrict__ Whi,
                                                  const ushort_t* __restrict__ Wlo,
                                                  const float* __restrict__ bias,
                                                  const float* __restrict__ uu3, int uuidx,
                                                  const float* __restrict__ raw_c,
                                                  unsigned int* __restrict__ outH,
                                                  int n, int nWaves){
  __shared__ ushort_t Wsh[2][128*128];   // 64 KB: [0]=hi, [1]=lo, swizzled
  int tid = threadIdx.x;
  {
    const uint4* gh = (const uint4*)Whi;
    const uint4* gl = (const uint4*)Wlo;
    uint4* sh = (uint4*)Wsh[0];
    uint4* sl = (uint4*)Wsh[1];
    #pragma unroll
    for (int i = 0; i < 8; ++i){
      int idx = tid + 256*i;
      int sw = idx ^ ((idx >> 4) & 7);
      sh[sw] = gh[idx];
    }
    #pragma unroll
    for (int i = 0; i < 8; ++i){
      int idx = tid + 256*i;
      int sw = idx ^ ((idx >> 4) & 7);
      sl[sw] = gl[idx];
    }
  }
  __syncthreads();

  int lane = tid & 63;
  int c = lane & 15, quad = lane >> 4;
  int wid = blockIdx.x * 4 + (tid >> 6);
  int nStrips = (n + 15) >> 4;
  int csw = (c & 7) << 3;

  float K, sK; get_c(raw_c, K, sK);
  float uu = uu3[uuidx];
  float uv[8];
  #pragma unroll
  for (int t = 0; t < 8; ++t){
    int col = t*16 + c;
    uv[t] = (col == 0) ? 0.f : bias[col];
  }

  for (int strip = wid; strip < nStrips; strip += nWaves){
    int m0 = strip * 16;
    int ra = m0 + c; if (ra > n - 1) ra = n - 1;
    short8 ahi[4], alo[4];
    #pragma unroll
    for (int kc = 0; kc < 4; ++kc){
      size_t aoff = (size_t)ra*128 + kc*32 + quad*8;
      ahi[kc] = *(const short8*)&Ahi[aoff];
      alo[kc] = *(const short8*)&Alo[aoff];
    }

    f32x4 acc[8];
    #pragma unroll
    for (int t = 0; t < 8; ++t){
      f32x4 z = {0.f, 0.f, 0.f, 0.f};
      acc[t] = z;
      int wrow = (t*16 + c) * 128;
      #pragma unroll
      for (int kc = 0; kc < 4; ++kc){
        int woff = (wrow + kc*32 + quad*8) ^ csw;
        short8 bhi = *(const short8*)&Wsh[0][woff];
        short8 blo = *(const short8*)&Wsh[1][woff];
        acc[t] = __builtin_amdgcn_mfma_f32_16x16x32_bf16(ahi[kc], bhi, acc[t], 0, 0, 0);
        acc[t] = __builtin_amdgcn_mfma_f32_16x16x32_bf16(ahi[kc], blo, acc[t], 0, 0, 0);
        acc[t] = __builtin_amdgcn_mfma_f32_16x16x32_bf16(alo[kc], bhi, acc[t], 0, 0, 0);
      }
    }

    if (c == 0){ f32x4 z = {0.f,0.f,0.f,0.f}; acc[0] = z; }
    #pragma unroll
    for (int r = 0; r < 4; ++r){
      float tt = 0.f, tu = 0.f;
      #pragma unroll
      for (int t = 0; t < 8; ++t){
        float v = acc[t][r];
        tt = fmaf(v, v, tt);
        tu = fmaf(v, uv[t], tu);
      }
      #pragma unroll
      for (int m = 1; m <= 8; m <<= 1){
        tt += __shfl_xor(tt, m);
        tu += __shfl_xor(tu, m);
      }
      float At, Au; chain_scalars(tt, tu, uu, K, sK, At, Au);
      int row = m0 + quad*4 + r;
      #pragma unroll
      for (int t = 0; t < 8; ++t){
        float o  = fmaf(At, acc[t][r], Au*uv[t]);
        float on = __shfl_xor(o, 1);
        if (row < n && !(c & 1))
          outH[(size_t)row*64 + t*8 + (c >> 1)] = pack_bf16(o, on);
      }
    }
  }
}

// --------------------------- CSR build -------------------------------------
__global__ __launch_bounds__(256) void hist_k(const int* __restrict__ rows,
                                              int* __restrict__ cnt,
                                              int* __restrict__ rnk, int e){
  int base = (blockIdx.x * 256 + threadIdx.x) * 4;
  if (base + 3 < e){
    int4 r = *(const int4*)&rows[base];
    int k0 = atomicAdd(&cnt[r.x], 1);
    int k1 = atomicAdd(&cnt[r.y], 1);
    int k2 = atomicAdd(&cnt[r.z], 1);
    int k3 = atomicAdd(&cnt[r.w], 1);
    *(int4*)&rnk[base] = make_int4(k0, k1, k2, k3);
  } else {
    for (int i = base; i < e; ++i) rnk[i] = atomicAdd(&cnt[rows[i]], 1);
  }
}

#define SCAN_ITEMS 4
__global__ __launch_bounds__(256) void scan1(const int* __restrict__ cnt,
                                             int* __restrict__ off,
                                             int* __restrict__ bsum, int n){
  __shared__ int sh[256];
  int tid = threadIdx.x;
  int base = blockIdx.x * 256 * SCAN_ITEMS + tid * SCAN_ITEMS;
  int v[SCAN_ITEMS]; int s = 0;
  #pragma unroll
  for (int i = 0; i < SCAN_ITEMS; ++i){ int idx = base+i; v[i] = (idx < n) ? cnt[idx] : 0; s += v[i]; }
  sh[tid] = s; __syncthreads();
  for (int o = 1; o < 256; o <<= 1){
    int t = (tid >= o) ? sh[tid - o] : 0; __syncthreads();
    sh[tid] += t; __syncthreads();
  }
  int excl = sh[tid] - s;
  if (tid == 255) bsum[blockIdx.x] = sh[tid];
  int run = excl;
  #pragma unroll
  for (int i = 0; i < SCAN_ITEMS; ++i){ int idx = base+i; if (idx < n) off[idx] = run; run += v[i]; }
}

// parallel exclusive scan of block sums (G <= 256; G = ceil(N/1024) = 98)
__global__ __launch_bounds__(256) void scan2(int* __restrict__ bsum, int G){
  __shared__ int sh[256];
  int t = threadIdx.x;
  int v = (t < G) ? bsum[t] : 0;
  sh[t] = v; __syncthreads();
  for (int o = 1; o < 256; o <<= 1){
    int x = (t >= o) ? sh[t - o] : 0; __syncthreads();
    sh[t] += x; __syncthreads();
  }
  if (t < G) bsum[t] = sh[t] - v;
}

// fill with consumer-side bsum add (scan3 eliminated)
__global__ __launch_bounds__(256) void fill_k(const int* __restrict__ rows,
                                              const int* __restrict__ cols,
                                              const float* __restrict__ vals,
                                              const int* __restrict__ off,
                                              const int* __restrict__ bsum,
                                              const int* __restrict__ rnk,
                                              int2* __restrict__ ecv, int e){
  int base = (blockIdx.x * 256 + threadIdx.x) * 4;
  if (base + 3 < e){
    int4   r = *(const int4*)&rows[base];
    int4   q = *(const int4*)&rnk[base];
    int4   c = *(const int4*)&cols[base];
    float4 v = *(const float4*)&vals[base];
    int o0 = off[r.x] + bsum[r.x >> 10];
    int o1 = off[r.y] + bsum[r.y >> 10];
    int o2 = off[r.z] + bsum[r.z >> 10];
    int o3 = off[r.w] + bsum[r.w >> 10];
    ecv[o0 + q.x] = make_int2(c.x, __float_as_int(v.x));
    ecv[o1 + q.y] = make_int2(c.y, __float_as_int(v.y));
    ecv[o2 + q.z] = make_int2(c.z, __float_as_int(v.z));
    ecv[o3 + q.w] = make_int2(c.w, __float_as_int(v.w));
  } else {
    for (int i = base; i < e; ++i)
      ecv[off[rows[i]] + bsum[rows[i] >> 10] + rnk[i]] = make_int2(cols[i], __float_as_int(vals[i]));
  }
}

// --------------------------- seg-sum (bf16 table, int2 edges) ---------------
__device__ __forceinline__ float2 seg_gather_bf16(const unsigned int* __restrict__ h,
                                                  const int* __restrict__ off,
                                                  const int* __restrict__ bsum,
                                                  const int* __restrict__ cnt,
                                                  const int2* __restrict__ ecv,
                                                  int row, int lane){
  float ax = 0.f, ay = 0.f, bx = 0.f, by = 0.f;
  int st = off[row] + bsum[row >> 10], deg = cnt[row];
  const unsigned int* __restrict__ hb = h + lane;   // row stride = 64 uints
  for (int b = 0; b < deg; b += 64){
    int k = b + lane;
    int cc = 0; float vv = 0.f;
    if (k < deg){ int2 e = ecv[st+k]; cc = e.x; vv = __int_as_float(e.y); }
    int m = min(64, deg - b);
    for (int j = 0; j < m; j += 8){
      int   c0=__shfl(cc,j+0), c1=__shfl(cc,j+1), c2=__shfl(cc,j+2), c3=__shfl(cc,j+3);
      int   c4=__shfl(cc,j+4), c5=__shfl(cc,j+5), c6=__shfl(cc,j+6), c7=__shfl(cc,j+7);
      float v0=__shfl(vv,j+0), v1=__shfl(vv,j+1), v2=__shfl(vv,j+2), v3=__shfl(vv,j+3);
      float v4=__shfl(vv,j+4), v5=__shfl(vv,j+5), v6=__shfl(vv,j+6), v7=__shfl(vv,j+7);
      unsigned int p0 = hb[(size_t)c0*64];
      unsigned int p1 = hb[(size_t)c1*64];
      unsigned int p2 = hb[(size_t)c2*64];
      unsigned int p3 = hb[(size_t)c3*64];
      unsigned int p4 = hb[(size_t)c4*64];
      unsigned int p5 = hb[(size_t)c5*64];
      unsigned int p6 = hb[(size_t)c6*64];
      unsigned int p7 = hb[(size_t)c7*64];
      ax = fmaf(v0, bf_lo(p0), ax); ay = fmaf(v0, bf_hi(p0), ay);
      bx = fmaf(v1, bf_lo(p1), bx); by = fmaf(v1, bf_hi(p1), by);
      ax = fmaf(v2, bf_lo(p2), ax); ay = fmaf(v2, bf_hi(p2), ay);
      bx = fmaf(v3, bf_lo(p3), bx); by = fmaf(v3, bf_hi(p3), by);
      ax = fmaf(v4, bf_lo(p4), ax); ay = fmaf(v4, bf_hi(p4), ay);
      bx = fmaf(v5, bf_lo(p5), bx); by = fmaf(v5, bf_hi(p5), by);
      ax = fmaf(v6, bf_lo(p6), ax); ay = fmaf(v6, bf_hi(p6), ay);
      bx = fmaf(v7, bf_lo(p7), bx); by = fmaf(v7, bf_hi(p7), by);
    }
  }
  return make_float2(ax + bx, ay + by);
}

// ------ seg_x1: Lx1 = (1-n)*segsum(h1) + n*loga1 -> bf16 hi/lo split --------
__global__ __launch_bounds__(256) void seg_x1(const unsigned int* __restrict__ h1,
                                              const int* __restrict__ off,
                                              const int* __restrict__ bsum,
                                              const int* __restrict__ cnt,
                                              const int2* __restrict__ ecv,
                                              const float* __restrict__ loga1,
                                              const float* __restrict__ nparam,
                                              unsigned int* __restrict__ X1hi,
                                              unsigned int* __restrict__ X1lo, int n){
  int row  = (int)((blockIdx.x * blockDim.x + threadIdx.x) >> 6);
  int lane = threadIdx.x & 63;
  if (row >= n) return;
  float2 acc = seg_gather_bf16(h1, off, bsum, cnt, ecv, row, lane);
  float nv = nparam[row];
  float2 la1 = *(const float2*)&loga1[(size_t)row*128 + 2*lane];
  float ox = (1.f-nv)*acc.x + nv*la1.x;
  float oy = (1.f-nv)*acc.y + nv*la1.y;
  unsigned int hp = pack_bf16(ox, oy);
  X1hi[(size_t)row*64 + lane] = hp;
  X1lo[(size_t)row*64 + lane] = pack_bf16(ox - bf_lo(hp), oy - bf_hi(hp));
}

// ------------------- seg_x2: Lx2 = segsum(h2)  (packed bf16 out) ------------
__global__ __launch_bounds__(256) void seg_x2(const unsigned int* __restrict__ h2,
                                              const int* __restrict__ off,
                                              const int* __restrict__ bsum,
                                              const int* __restrict__ cnt,
                                              const int2* __restrict__ ecv,
                                              unsigned int* __restrict__ Lx2p, int n){
  int row  = (int)((blockIdx.x * blockDim.x + threadIdx.x) >> 6);
  int lane = threadIdx.x & 63;
  if (row >= n) return;
  float2 acc = seg_gather_bf16(h2, off, bsum, cnt, ecv, row, lane);
  Lx2p[(size_t)row*64 + lane] = pack_bf16(acc.x, acc.y);
}

// --------------------------- batch head -------------------------------------
// d<64: s2 gather from packed-bf16 Lx2; d>=64: s3 gather from fp32 loga1.
__global__ __launch_bounds__(128) void batch_head(const unsigned int* __restrict__ Lx2p,
                                                  const float* __restrict__ loga1,
                                                  const int* __restrict__ bidx,
                                                  const float* __restrict__ weight,
                                                  const float* __restrict__ weight2,
                                                  const float* __restrict__ c1w,
                                                  const float* __restrict__ c1b,
                                                  const float* __restrict__ c2w,
                                                  const float* __restrict__ c2b,
                                                  const float* __restrict__ cls,
                                                  const float* __restrict__ clsb,
                                                  float* __restrict__ out, int Bn){
  __shared__ float sg2[128], sg3[128], ssel[100], spre[5];
  __shared__ int sbi[50];
  __shared__ float sc1[50], sc2[50];
  int b = blockIdx.x, d = threadIdx.x;
  const int* bi = bidx + (size_t)b * 50;
  if (d < 50){ sbi[d] = bi[d]; sc1[d] = c1w[d]; sc2[d] = c2w[d]; }
  __syncthreads();
  int lane = d & 63;
  bool lo = d < 64;
  float gx = 0.f, gy = 0.f;
  if (lo){
    const unsigned int* __restrict__ tp = Lx2p + lane;   // row stride 64 uints
    #pragma unroll
    for (int l = 0; l < 50; l += 5){
      int i0 = sbi[l+0], i1 = sbi[l+1], i2 = sbi[l+2], i3 = sbi[l+3], i4 = sbi[l+4];
      unsigned int p0 = tp[(size_t)i0*64];
      unsigned int p1 = tp[(size_t)i1*64];
      unsigned int p2 = tp[(size_t)i2*64];
      unsigned int p3 = tp[(size_t)i3*64];
      unsigned int p4 = tp[(size_t)i4*64];
      float w0 = sc1[l+0], w1 = sc1[l+1], w2 = sc1[l+2], w3 = sc1[l+3], w4 = sc1[l+4];
      gx = fmaf(w0, bf_lo(p0), gx); gy = fmaf(w0, bf_hi(p0), gy);
      gx = fmaf(w1, bf_lo(p1), gx); gy = fmaf(w1, bf_hi(p1), gy);
      gx = fmaf(w2, bf_lo(p2), gx); gy = fmaf(w2, bf_hi(p2), gy);
      gx = fmaf(w3, bf_lo(p3), gx); gy = fmaf(w3, bf_hi(p3), gy);
      gx = fmaf(w4, bf_lo(p4), gx); gy = fmaf(w4, bf_hi(p4), gy);
    }
    sg2[2*lane] = gx; sg2[2*lane+1] = gy;
  } else {
    const float2* __restrict__ t2 = (const float2*)loga1 + lane;  // row stride 64
    #pragma unroll
    for (int l = 0; l < 50; l += 5){
      int i0 = sbi[l+0], i1 = sbi[l+1], i2 = sbi[l+2], i3 = sbi[l+3], i4 = sbi[l+4];
      float2 p0 = t2[(size_t)i0*64];
      float2 p1 = t2[(size_t)i1*64];
      float2 p2 = t2[(size_t)i2*64];
      float2 p3 = t2[(size_t)i3*64];
      float2 p4 = t2[(size_t)i4*64];
      float w0 = sc2[l+0], w1 = sc2[l+1], w2 = sc2[l+2], w3 = sc2[l+3], w4 = sc2[l+4];
      gx = fmaf(w0, p0.x, gx); gy = fmaf(w0, p0.y, gy);
      gx = fmaf(w1, p1.x, gx); gy = fmaf(w1, p1.y, gy);
      gx = fmaf(w2, p2.x, gx); gy = fmaf(w2, p2.y, gy);
      gx = fmaf(w3, p3.x, gx); gy = fmaf(w3, p3.y, gy);
      gx = fmaf(w4, p4.x, gx); gy = fmaf(w4, p4.y, gy);
    }
    sg3[2*lane] = gx; sg3[2*lane+1] = gy;
  }
  __syncthreads();
  if (d < 50){
    float s = 0.f;
    for (int k = 0; k < 128; ++k) s = fmaf(sg2[k], weight[k*50 + d], s);
    s += c1b[0];
    ssel[d] = s;
    out[(size_t)Bn + (size_t)b*100 + d] = s;
  } else if (d >= 64 && d < 114){
    int t = d - 64;
    float s = 0.f;
    for (int k = 0; k < 128; ++k) s = fmaf(sg3[k], weight2[k*50 + t], s);
    s += c2b[0];
    ssel[50 + t] = s;
    out[(size_t)Bn + (size_t)b*100 + 50 + t] = s;
  }
  __syncthreads();
  if (d < 5){
    float s = clsb[d];
    for (int j = 0; j < 100; ++j) s = fmaf(ssel[j], cls[j*5 + d], s);
    spre[d] = s;
  }
  __syncthreads();
  if (d == 0){
    int best = 0; float bv = spre[0];
    #pragma unroll
    for (int k = 1; k < 5; ++k) if (spre[k] > bv){ bv = spre[k]; best = k; }
    out[b] = (float)best;
  }
}

// ---------------------------------------------------------------------------
extern "C" void kernel_launch(void* const* d_in, const int* in_sizes, int n_in,
                              void* d_out, int out_size, void* d_ws, size_t ws_size,
                              hipStream_t stream) {
  const float* A1     = (const float*)d_in[0];
  const int*   rows   = (const int*)  d_in[1];
  const int*   cols   = (const int*)  d_in[2];
  const float* vals   = (const float*)d_in[3];
  const int*   bidx   = (const int*)  d_in[4];
  const float* raw_c  = (const float*)d_in[5];
  const float* nparam = (const float*)d_in[6];
  const float* Lin1   = (const float*)d_in[7];
  const float* Lin1_b = (const float*)d_in[8];
  const float* gc1_w  = (const float*)d_in[9];
  const float* gc1_b  = (const float*)d_in[10];
  const float* gc2_w  = (const float*)d_in[11];
  const float* gc2_b  = (const float*)d_in[12];
  const float* weight = (const float*)d_in[13];
  const float* weight2= (const float*)d_in[14];
  const float* c1w    = (const float*)d_in[15];
  const float* c1b    = (const float*)d_in[16];
  const float* c2w    = (const float*)d_in[17];
  const float* c2b    = (const float*)d_in[18];
  const float* cls    = (const float*)d_in[19];
  const float* clsb   = (const float*)d_in[20];

  int N  = in_sizes[0] / 129;
  int E  = in_sizes[1];
  int Bn = in_sizes[4] / 50;
  size_t NF = (size_t)N * 128;

  // workspace layout (region 0: Lhi/Llo early, reused as packed Lx2 late)
  ushort_t* Lhi = (ushort_t*)d_ws;              // 2NF B
  ushort_t* Llo = Lhi + NF;                     // 2NF B
  unsigned int* Lx2p = (unsigned int*)d_ws;     // Lx2 packed bf16 (aliases Lhi/Llo)
  float*    S3  = (float*)(Llo + NF);           // loga1 fp32, 4NF B
  unsigned int* Hb   = (unsigned int*)(S3 + NF);  // h1/h2 bf16, NF/2 uints
  unsigned int* X1hi = Hb + NF/2;               // Lx1 hi
  unsigned int* X1lo = X1hi + NF/2;             // Lx1 lo
  ushort_t* Wb = (ushort_t*)(X1lo + NF/2);      // 6 x 16384 ushorts (W1h,W1l,W2h,W2l,W3h,W3l)
  ushort_t* W3h = Wb + 4*16384, *W3l = Wb + 5*16384;
  int* cnt    = (int*)(Wb + 6*16384);
  int* off    = cnt + N;
  int* rnk    = off + N;
  int* bsum   = rnk + E;
  int2* ecv   = (int2*)(bsum + 4096);
  float* uu3  = (float*)(ecv + E);

  int rowBlocks  = (N + 3) / 4;
  int G = (N + 256*SCAN_ITEMS - 1) / (256*SCAN_ITEMS);
  int eBlocks4 = (E/4 + 255) / 256 + 1;
  int sBlocks = (int)(((size_t)N*32 + 255)/256);

  // prep: stage_a + W splits + cnt zero + uu3 (one launch)
  prep<<<sBlocks + 192, 256, 0, stream>>>(A1, Lhi, Llo, cnt, Lin1, gc1_w, gc2_w,
                                          Wb, Lin1_b, gc1_b, gc2_b, uu3, N, sBlocks);

  hist_k<<<eBlocks4, 256, 0, stream>>>(rows, cnt, rnk, E);
  scan1<<<G, 256, 0, stream>>>(cnt, off, bsum, N);
  scan2<<<1, 256, 0, stream>>>(bsum, G);
  fill_k<<<eBlocks4, 256, 0, stream>>>(rows, cols, vals, off, bsum, rnk, ecv, E);

  // loga1 (fp32 -> S3) + h1 (packed -> Hb), A tables read once
  mfma12<<<256, 512, 0, stream>>>(Lhi, Llo, Wb, Lin1_b, gc1_b, uu3, raw_c,
                                  S3, Hb, N, 256*8);
  seg_x1<<<rowBlocks, 256, 0, stream>>>(Hb, off, bsum, cnt, ecv, S3, nparam,
                                        X1hi, X1lo, N);
  // h2 = chain(Lx1@gc2_w, gc2_b) -> Hb (bf16); X1 packed tables
  mfma_chain<<<512, 256, 0, stream>>>((const ushort_t*)X1hi, (const ushort_t*)X1lo,
                                      W3h, W3l, gc2_b, uu3, 2, raw_c,
                                      Hb, N, 512*4);
  seg_x2<<<rowBlocks, 256, 0, stream>>>(Hb, off, bsum, cnt, ecv, Lx2p, N);
  batch_head<<<Bn, 128, 0, stream>>>(Lx2p, S3, bidx, weight, weight2, c1w, c1b,
                                     c2w, c2b, cls, clsb, (float*)d_out, Bn);
}

// Round 6
// 561.894 us; speedup vs baseline: 1.3288x; 1.3034x over previous
//
#include <hip/hip_runtime.h>
#include <math.h>

// ---------------------------------------------------------------------------
// Hyperbolic GCN forward, fully collapsed (round-2 skeleton, best=576us):
//  - logmap0(proj(expmap0(u))) == u ; bias chain is affine (At,Au per row)
//  - ALL GEMMs on matrix cores via split-bf16 (x = hi + lo, 3 MFMA passes),
//    W (hi+lo, 64 KB) staged in LDS (XOR-swizzled), 512 blocks, 2/CU.
//  - Round-6: hist overlapped with stage_a/split_w via BLOCK-role split in
//    one prep kernel (hist blocks first -> full TLP for atomics; streaming
//    blocks pipeline behind; disjoint resources: fabric-atomics vs HBM BW).
//    cnt zeroed by hipMemsetAsync (race-free). scan3 folded into consumers.
//  - Round-4/5 lesson: the 128KB-LDS fused mfma (mfma12/mfma_dual) inflates
//    FETCH/WRITE ~4x (spill or unknown pathology) -> ABANDONED; 64KB/2-block
//    mfma_chain is the known-good config.
//  - Round-3 lesson: keep CSR compact + separate hist/fill passes.
//  - Round-1 lesson: scatter/atomic work keeps massive grids (never 1-2
//    aux waves inside LDS-heavy blocks).
// ---------------------------------------------------------------------------

typedef unsigned short ushort_t;
typedef __attribute__((ext_vector_type(8))) short short8;
typedef __attribute__((ext_vector_type(4))) float f32x4;
typedef __attribute__((ext_vector_type(4))) unsigned short u16x4;

__device__ __forceinline__ float wsum(float x){
  x += __shfl_xor(x, 32);
  x += __shfl_xor(x, 16);
  x += __shfl_xor(x, 8);
  x += __shfl_xor(x, 4);
  x += __shfl_xor(x, 2);
  x += __shfl_xor(x, 1);
  return x;
}

__device__ __forceinline__ void get_c(const float* rc, float& K, float& sK){
  float c = log1pf(expf(rc[0])) + 1e-5f;   // softplus(raw_c) + 1e-5
  K  = 1.0f / c;
  sK = sqrtf(K);
}

__device__ __forceinline__ float sinhx_over_x(float x){
  if (x > 1e-3f){
    float e  = __expf(x);
    float em = __builtin_amdgcn_rcpf(e);
    return 0.5f*(e - em) * __builtin_amdgcn_rcpf(x);
  }
  return 1.0f + x*x*(1.0f/6.0f);
}

__device__ __forceinline__ float facosh(float x){   // x >= 1+1e-7
  return __logf(x + sqrtf(fmaxf(fmaf(x, x, -1.0f), 0.0f)));
}

__device__ __forceinline__ ushort_t bf16_rne(float x){
  unsigned int u = __float_as_uint(x);
  u += 0x7fffu + ((u >> 16) & 1u);
  return (ushort_t)(u >> 16);
}
__device__ __forceinline__ float bf2f(ushort_t h){
  return __uint_as_float(((unsigned int)h) << 16);
}
__device__ __forceinline__ unsigned int pack_bf16(float x, float y){
  unsigned int bx = __float_as_uint(x);
  unsigned int by = __float_as_uint(y);
  bx = (bx + 0x7fffu + ((bx >> 16) & 1u)) >> 16;
  by = (by + 0x7fffu + ((by >> 16) & 1u)) & 0xffff0000u;
  return bx | by;
}
__device__ __forceinline__ float bf_lo(unsigned int p){ return __uint_as_float(p << 16); }
__device__ __forceinline__ float bf_hi(unsigned int p){ return __uint_as_float(p & 0xffff0000u); }

// Chain scalars: out_j = At*t_j + Au*u_j == logmap0(mobius_add(exp-chain)).
__device__ __forceinline__ void chain_scalars(float tt, float tu, float uu,
                                              float K, float sK,
                                              float& At, float& Au){
  float xn  = fmaxf(sqrtf(tt), 1e-15f);
  float th  = xn / sK;
  float f   = sinhx_over_x(th);
  float pn2 = f*f*tt;
  float p0  = sqrtf(fmaxf(K + pn2, 1e-7f));
  float S_yu = f * tu;
  float yn  = fmaxf(sqrtf(pn2), 1e-15f);
  float inv_yn = __builtin_amdgcn_rcpf(yn);
  float alpha = S_yu * inv_yn / sK;
  float coef  = alpha * (sK - p0);
  float cy  = coef * inv_yn;
  float cyf = cy * f;
  float pdw  = S_yu - cy*pn2;
  float spsq = uu - 2.f*cy*S_yu + cy*cy*pn2;
  float w0 = pdw / fmaxf(p0, 1e-7f);
  float md = spsq - w0*w0;
  float normu = fminf(sqrtf(fmaxf(md, 1e-7f)), 1e6f);
  float th2 = fmaxf(normu / sK, 1e-15f);
  float e  = __expf(th2);
  float em = __builtin_amdgcn_rcpf(e);
  float ch = 0.5f*(e + em);
  float g  = (th2 > 1e-3f) ? 0.5f*(e - em)*__builtin_amdgcn_rcpf(th2)
                           : 1.0f + th2*th2*(1.0f/6.0f);
  float rn2 = ch*ch*pn2 + 2.f*ch*g*pdw + g*g*spsq;
  float r0 = sqrtf(fmaxf(K + rn2, 1e-7f));
  float ynf = fmaxf(sqrtf(rn2), 1e-15f);
  float thf = fmaxf(r0/sK, 1.f+1e-7f);
  float rf = sK * facosh(thf) * __builtin_amdgcn_rcpf(ynf);
  At = rf*(ch*f - g*cyf);
  Au = rf*g;
}

// ---------- prep: [0,histB) hist atomics | [histB,+sB) stage_a | [+192) W ---
// hist blocks FIRST so the atomic-rate-bound work (the long pole, ~69us)
// starts immediately; streaming blocks pipeline in behind it on HBM BW.
// cnt is zeroed by hipMemsetAsync before this kernel (same stream).
__global__ __launch_bounds__(256) void prep(const int* __restrict__ rows,
                                            int* __restrict__ cnt,
                                            int* __restrict__ rnk, int e,
                                            const float* __restrict__ A1,
                                            ushort_t* __restrict__ Lhi,
                                            ushort_t* __restrict__ Llo,
                                            const float* __restrict__ Lin1,
                                            const float* __restrict__ G1,
                                            const float* __restrict__ G2,
                                            ushort_t* __restrict__ Wb,
                                            const float* __restrict__ b0,
                                            const float* __restrict__ b1,
                                            const float* __restrict__ b2,
                                            float* __restrict__ uu3,
                                            int n, int histB, int sBlocks){
  int bid = blockIdx.x;
  if (bid < histB){
    // ---- histogram: one returning atomic per edge, rank saved ----
    int base = (bid * 256 + threadIdx.x) * 4;
    if (base + 3 < e){
      int4 r = *(const int4*)&rows[base];
      int k0 = atomicAdd(&cnt[r.x], 1);
      int k1 = atomicAdd(&cnt[r.y], 1);
      int k2 = atomicAdd(&cnt[r.z], 1);
      int k3 = atomicAdd(&cnt[r.w], 1);
      *(int4*)&rnk[base] = make_int4(k0, k1, k2, k3);
    } else {
      for (int i = base; i < e; ++i) rnk[i] = atomicAdd(&cnt[rows[i]], 1);
    }
  } else if (bid < histB + sBlocks){
    // ---- stage_a: split A1[:,1:] -> bf16 hi/lo tables (4 elems/thread) ----
    int sb = bid - histB;
    size_t i4 = (size_t)sb * 256 + threadIdx.x;
    size_t tot4 = (size_t)n * 32;
    if (i4 < tot4){
      size_t row = i4 >> 5; int j0 = (int)(i4 & 31) * 4;
      const float* s = A1 + row*129 + 1 + j0;
      float v0 = s[0], v1 = s[1], v2 = s[2], v3 = s[3];
      ushort_t h0 = bf16_rne(v0), h1 = bf16_rne(v1), h2 = bf16_rne(v2), h3 = bf16_rne(v3);
      u16x4 hh = {h0, h1, h2, h3};
      u16x4 ll = {bf16_rne(v0 - bf2f(h0)), bf16_rne(v1 - bf2f(h1)),
                  bf16_rne(v2 - bf2f(h2)), bf16_rne(v3 - bf2f(h3))};
      *(u16x4*)&Lhi[i4*4] = hh;
      *(u16x4*)&Llo[i4*4] = ll;
    }
    if (sb == 0 && threadIdx.x < 64){
      int lane = threadIdx.x;
      const float* bs[3] = {b0, b1, b2};
      for (int k = 0; k < 3; ++k){
        float x = lane ? bs[k][2*lane] : 0.0f;
        float y = bs[k][2*lane+1];
        float s = wsum(x*x + y*y);
        if (lane == 0) uu3[k] = s;
      }
    }
  } else {
    // ---- split+transpose the three 128x128 weights ----
    int wb = bid - histB - sBlocks;  // 0..191
    int which = wb >> 6, b = wb & 63;
    const float* W = (which == 0) ? (Lin1 + 128) : (which == 1) ? (G1 + 128) : G2;
    ushort_t* Whi = Wb + (size_t)which * 2 * 16384;
    ushort_t* Wlo = Whi + 16384;
    int id = b * 256 + threadIdx.x;   // 0..16383
    int k = id >> 7, nn = id & 127;
    float v = W[(size_t)k*128 + nn];
    ushort_t h = bf16_rne(v);
    Whi[(size_t)nn*128 + k] = h;
    Wlo[(size_t)nn*128 + k] = bf16_rne(v - bf2f(h));
  }
}

// ---------- MFMA GEMM (split-bf16 x3), W staged in LDS, grid-stride strips --
// Round-2 validated config: 64 KB LDS, 512 blocks x 256 thr (2 blocks/CU).
// LDS XOR swizzle kills the 16-way W-read bank conflict (3.67M -> ~0).
__global__ __launch_bounds__(256) void mfma_chain(const ushort_t* __restrict__ Ahi,
                                                  const ushort_t* __restrict__ Alo,
                                                  const ushort_t* __restrict__ Whi,
                                                  const ushort_t* __restrict__ Wlo,
                                                  const float* __restrict__ bias,
                                                  const float* __restrict__ uu3, int uuidx,
                                                  const float* __restrict__ raw_c,
                                                  float* __restrict__ outF,
                                                  unsigned int* __restrict__ outH,
                                                  int mode, int n, int nWaves){
  __shared__ ushort_t Wsh[2][128*128];   // 64 KB: [0]=hi, [1]=lo, swizzled
  int tid = threadIdx.x;
  {
    const uint4* gh = (const uint4*)Whi;
    const uint4* gl = (const uint4*)Wlo;
    uint4* sh = (uint4*)Wsh[0];
    uint4* sl = (uint4*)Wsh[1];
    #pragma unroll
    for (int i = 0; i < 8; ++i){
      int idx = tid + 256*i;
      int sw = idx ^ ((idx >> 4) & 7);      // uint4-index swizzle == byte^((n&7)<<4)
      sh[sw] = gh[idx];
    }
    #pragma unroll
    for (int i = 0; i < 8; ++i){
      int idx = tid + 256*i;
      int sw = idx ^ ((idx >> 4) & 7);
      sl[sw] = gl[idx];
    }
  }
  __syncthreads();

  int lane = tid & 63;
  int c = lane & 15, quad = lane >> 4;
  int wid = blockIdx.x * 4 + (tid >> 6);
  int nStrips = (n + 15) >> 4;
  int csw = (c & 7) << 3;                   // ushort-index swizzle for reads

  float K, sK; get_c(raw_c, K, sK);
  float uu = uu3[uuidx];
  float uv[8];
  #pragma unroll
  for (int t = 0; t < 8; ++t){
    int col = t*16 + c;
    uv[t] = (col == 0) ? 0.f : bias[col];
  }

  for (int strip = wid; strip < nStrips; strip += nWaves){
    int m0 = strip * 16;
    int ra = m0 + c; if (ra > n - 1) ra = n - 1;
    short8 ahi[4], alo[4];
    #pragma unroll
    for (int kc = 0; kc < 4; ++kc){
      size_t aoff = (size_t)ra*128 + kc*32 + quad*8;
      ahi[kc] = *(const short8*)&Ahi[aoff];
      alo[kc] = *(const short8*)&Alo[aoff];
    }

    f32x4 acc[8];
    #pragma unroll
    for (int t = 0; t < 8; ++t){
      f32x4 z = {0.f, 0.f, 0.f, 0.f};
      acc[t] = z;
      int wrow = (t*16 + c) * 128;
      #pragma unroll
      for (int kc = 0; kc < 4; ++kc){
        int woff = (wrow + kc*32 + quad*8) ^ csw;
        short8 bhi = *(const short8*)&Wsh[0][woff];
        short8 blo = *(const short8*)&Wsh[1][woff];
        acc[t] = __builtin_amdgcn_mfma_f32_16x16x32_bf16(ahi[kc], bhi, acc[t], 0, 0, 0);
        acc[t] = __builtin_amdgcn_mfma_f32_16x16x32_bf16(ahi[kc], blo, acc[t], 0, 0, 0);
        acc[t] = __builtin_amdgcn_mfma_f32_16x16x32_bf16(alo[kc], bhi, acc[t], 0, 0, 0);
      }
    }

    if (c == 0){                     // output col 0 = time component, dropped
      f32x4 z = {0.f, 0.f, 0.f, 0.f};
      acc[0] = z;
    }
    #pragma unroll
    for (int r = 0; r < 4; ++r){
      float tt = 0.f, tu = 0.f;
      #pragma unroll
      for (int t = 0; t < 8; ++t){
        float v = acc[t][r];
        tt = fmaf(v, v, tt);
        tu = fmaf(v, uv[t], tu);
      }
      #pragma unroll
      for (int m = 1; m <= 8; m <<= 1){   // reduce across 16 lanes of the quad
        tt += __shfl_xor(tt, m);
        tu += __shfl_xor(tu, m);
      }
      float At, Au; chain_scalars(tt, tu, uu, K, sK, At, Au);
      int row = m0 + quad*4 + r;
      if (mode == 0){
        if (row < n){
          #pragma unroll
          for (int t = 0; t < 8; ++t){
            float o = fmaf(At, acc[t][r], Au*uv[t]);
            outF[(size_t)row*128 + t*16 + c] = o;
          }
        }
      } else {
        #pragma unroll
        for (int t = 0; t < 8; ++t){
          float o  = fmaf(At, acc[t][r], Au*uv[t]);
          float on = __shfl_xor(o, 1);
          if (row < n && !(c & 1))
            outH[(size_t)row*64 + t*8 + (c >> 1)] = pack_bf16(o, on);
        }
      }
    }
  }
}

// --------------------------- CSR scans + fill -------------------------------
#define SCAN_ITEMS 4
__global__ __launch_bounds__(256) void scan1(const int* __restrict__ cnt,
                                             int* __restrict__ off,
                                             int* __restrict__ bsum, int n){
  __shared__ int sh[256];
  int tid = threadIdx.x;
  int base = blockIdx.x * 256 * SCAN_ITEMS + tid * SCAN_ITEMS;
  int v[SCAN_ITEMS]; int s = 0;
  #pragma unroll
  for (int i = 0; i < SCAN_ITEMS; ++i){ int idx = base+i; v[i] = (idx < n) ? cnt[idx] : 0; s += v[i]; }
  sh[tid] = s; __syncthreads();
  for (int o = 1; o < 256; o <<= 1){
    int t = (tid >= o) ? sh[tid - o] : 0; __syncthreads();
    sh[tid] += t; __syncthreads();
  }
  int excl = sh[tid] - s;
  if (tid == 255) bsum[blockIdx.x] = sh[tid];
  int run = excl;
  #pragma unroll
  for (int i = 0; i < SCAN_ITEMS; ++i){ int idx = base+i; if (idx < n) off[idx] = run; run += v[i]; }
}

// parallel exclusive scan of block sums (G <= 256; G = ceil(N/1024) = 98)
__global__ __launch_bounds__(256) void scan2(int* __restrict__ bsum, int G){
  __shared__ int sh[256];
  int t = threadIdx.x;
  int v = (t < G) ? bsum[t] : 0;
  sh[t] = v; __syncthreads();
  for (int o = 1; o < 256; o <<= 1){
    int x = (t >= o) ? sh[t - o] : 0; __syncthreads();
    sh[t] += x; __syncthreads();
  }
  if (t < G) bsum[t] = sh[t] - v;
}

// fill with consumer-side bsum add (scan3 eliminated; validated r4/r5)
__global__ __launch_bounds__(256) void fill_k(const int* __restrict__ rows,
                                              const int* __restrict__ cols,
                                              const float* __restrict__ vals,
                                              const int* __restrict__ off,
                                              const int* __restrict__ bsum,
                                              const int* __restrict__ rnk,
                                              int2* __restrict__ ecv, int e){
  int base = (blockIdx.x * 256 + threadIdx.x) * 4;
  if (base + 3 < e){
    int4   r = *(const int4*)&rows[base];
    int4   q = *(const int4*)&rnk[base];
    int4   c = *(const int4*)&cols[base];
    float4 v = *(const float4*)&vals[base];
    int o0 = off[r.x] + bsum[r.x >> 10];
    int o1 = off[r.y] + bsum[r.y >> 10];
    int o2 = off[r.z] + bsum[r.z >> 10];
    int o3 = off[r.w] + bsum[r.w >> 10];
    ecv[o0 + q.x] = make_int2(c.x, __float_as_int(v.x));
    ecv[o1 + q.y] = make_int2(c.y, __float_as_int(v.y));
    ecv[o2 + q.z] = make_int2(c.z, __float_as_int(v.z));
    ecv[o3 + q.w] = make_int2(c.w, __float_as_int(v.w));
  } else {
    for (int i = base; i < e; ++i)
      ecv[off[rows[i]] + bsum[rows[i] >> 10] + rnk[i]] = make_int2(cols[i], __float_as_int(vals[i]));
  }
}

// --------------------------- seg-sum (bf16 table, int2 edges) ---------------
__device__ __forceinline__ float2 seg_gather_bf16(const unsigned int* __restrict__ h,
                                                  const int* __restrict__ off,
                                                  const int* __restrict__ bsum,
                                                  const int* __restrict__ cnt,
                                                  const int2* __restrict__ ecv,
                                                  int row, int lane){
  float ax = 0.f, ay = 0.f, bx = 0.f, by = 0.f;
  int st = off[row] + bsum[row >> 10], deg = cnt[row];
  const unsigned int* __restrict__ hb = h + lane;   // row stride = 64 uints
  for (int b = 0; b < deg; b += 64){
    int k = b + lane;
    int cc = 0; float vv = 0.f;
    if (k < deg){ int2 e = ecv[st+k]; cc = e.x; vv = __int_as_float(e.y); }
    int m = min(64, deg - b);
    for (int j = 0; j < m; j += 8){
      int   c0=__shfl(cc,j+0), c1=__shfl(cc,j+1), c2=__shfl(cc,j+2), c3=__shfl(cc,j+3);
      int   c4=__shfl(cc,j+4), c5=__shfl(cc,j+5), c6=__shfl(cc,j+6), c7=__shfl(cc,j+7);
      float v0=__shfl(vv,j+0), v1=__shfl(vv,j+1), v2=__shfl(vv,j+2), v3=__shfl(vv,j+3);
      float v4=__shfl(vv,j+4), v5=__shfl(vv,j+5), v6=__shfl(vv,j+6), v7=__shfl(vv,j+7);
      unsigned int p0 = hb[(size_t)c0*64];
      unsigned int p1 = hb[(size_t)c1*64];
      unsigned int p2 = hb[(size_t)c2*64];
      unsigned int p3 = hb[(size_t)c3*64];
      unsigned int p4 = hb[(size_t)c4*64];
      unsigned int p5 = hb[(size_t)c5*64];
      unsigned int p6 = hb[(size_t)c6*64];
      unsigned int p7 = hb[(size_t)c7*64];
      ax = fmaf(v0, bf_lo(p0), ax); ay = fmaf(v0, bf_hi(p0), ay);
      bx = fmaf(v1, bf_lo(p1), bx); by = fmaf(v1, bf_hi(p1), by);
      ax = fmaf(v2, bf_lo(p2), ax); ay = fmaf(v2, bf_hi(p2), ay);
      bx = fmaf(v3, bf_lo(p3), bx); by = fmaf(v3, bf_hi(p3), by);
      ax = fmaf(v4, bf_lo(p4), ax); ay = fmaf(v4, bf_hi(p4), ay);
      bx = fmaf(v5, bf_lo(p5), bx); by = fmaf(v5, bf_hi(p5), by);
      ax = fmaf(v6, bf_lo(p6), ax); ay = fmaf(v6, bf_hi(p6), ay);
      bx = fmaf(v7, bf_lo(p7), bx); by = fmaf(v7, bf_hi(p7), by);
    }
  }
  return make_float2(ax + bx, ay + by);
}

// ------ seg_x1: Lx1 = (1-n)*segsum(h1) + n*loga1 -> bf16 hi/lo split --------
__global__ __launch_bounds__(256) void seg_x1(const unsigned int* __restrict__ h1,
                                              const int* __restrict__ off,
                                              const int* __restrict__ bsum,
                                              const int* __restrict__ cnt,
                                              const int2* __restrict__ ecv,
                                              const float* __restrict__ loga1,
                                              const float* __restrict__ nparam,
                                              unsigned int* __restrict__ X1hi,
                                              unsigned int* __restrict__ X1lo, int n){
  int row  = (int)((blockIdx.x * blockDim.x + threadIdx.x) >> 6);
  int lane = threadIdx.x & 63;
  if (row >= n) return;
  float2 acc = seg_gather_bf16(h1, off, bsum, cnt, ecv, row, lane);
  float nv = nparam[row];
  float2 la1 = *(const float2*)&loga1[(size_t)row*128 + 2*lane];
  float ox = (1.f-nv)*acc.x + nv*la1.x;
  float oy = (1.f-nv)*acc.y + nv*la1.y;
  unsigned int hp = pack_bf16(ox, oy);
  X1hi[(size_t)row*64 + lane] = hp;
  X1lo[(size_t)row*64 + lane] = pack_bf16(ox - bf_lo(hp), oy - bf_hi(hp));
}

// ------------------- seg_x2: Lx2 = segsum(h2)  (packed bf16 out) ------------
__global__ __launch_bounds__(256) void seg_x2(const unsigned int* __restrict__ h2,
                                              const int* __restrict__ off,
                                              const int* __restrict__ bsum,
                                              const int* __restrict__ cnt,
                                              const int2* __restrict__ ecv,
                                              unsigned int* __restrict__ Lx2p, int n){
  int row  = (int)((blockIdx.x * blockDim.x + threadIdx.x) >> 6);
  int lane = threadIdx.x & 63;
  if (row >= n) return;
  float2 acc = seg_gather_bf16(h2, off, bsum, cnt, ecv, row, lane);
  Lx2p[(size_t)row*64 + lane] = pack_bf16(acc.x, acc.y);
}

// --------------------------- batch head -------------------------------------
// d<64: s2 gather from packed-bf16 Lx2; d>=64: s3 gather from fp32 loga1.
__global__ __launch_bounds__(128) void batch_head(const unsigned int* __restrict__ Lx2p,
                                                  const float* __restrict__ loga1,
                                                  const int* __restrict__ bidx,
                                                  const float* __restrict__ weight,
                                                  const float* __restrict__ weight2,
                                                  const float* __restrict__ c1w,
                                                  const float* __restrict__ c1b,
                                                  const float* __restrict__ c2w,
                                                  const float* __restrict__ c2b,
                                                  const float* __restrict__ cls,
                                                  const float* __restrict__ clsb,
                                                  float* __restrict__ out, int Bn){
  __shared__ float sg2[128], sg3[128], ssel[100], spre[5];
  __shared__ int sbi[50];
  __shared__ float sc1[50], sc2[50];
  int b = blockIdx.x, d = threadIdx.x;
  const int* bi = bidx + (size_t)b * 50;
  if (d < 50){ sbi[d] = bi[d]; sc1[d] = c1w[d]; sc2[d] = c2w[d]; }
  __syncthreads();
  int lane = d & 63;
  bool lo = d < 64;
  float gx = 0.f, gy = 0.f;
  if (lo){
    const unsigned int* __restrict__ tp = Lx2p + lane;   // row stride 64 uints
    #pragma unroll
    for (int l = 0; l < 50; l += 5){
      int i0 = sbi[l+0], i1 = sbi[l+1], i2 = sbi[l+2], i3 = sbi[l+3], i4 = sbi[l+4];
      unsigned int p0 = tp[(size_t)i0*64];
      unsigned int p1 = tp[(size_t)i1*64];
      unsigned int p2 = tp[(size_t)i2*64];
      unsigned int p3 = tp[(size_t)i3*64];
      unsigned int p4 = tp[(size_t)i4*64];
      float w0 = sc1[l+0], w1 = sc1[l+1], w2 = sc1[l+2], w3 = sc1[l+3], w4 = sc1[l+4];
      gx = fmaf(w0, bf_lo(p0), gx); gy = fmaf(w0, bf_hi(p0), gy);
      gx = fmaf(w1, bf_lo(p1), gx); gy = fmaf(w1, bf_hi(p1), gy);
      gx = fmaf(w2, bf_lo(p2), gx); gy = fmaf(w2, bf_hi(p2), gy);
      gx = fmaf(w3, bf_lo(p3), gx); gy = fmaf(w3, bf_hi(p3), gy);
      gx = fmaf(w4, bf_lo(p4), gx); gy = fmaf(w4, bf_hi(p4), gy);
    }
    sg2[2*lane] = gx; sg2[2*lane+1] = gy;
  } else {
    const float2* __restrict__ t2 = (const float2*)loga1 + lane;  // row stride 64
    #pragma unroll
    for (int l = 0; l < 50; l += 5){
      int i0 = sbi[l+0], i1 = sbi[l+1], i2 = sbi[l+2], i3 = sbi[l+3], i4 = sbi[l+4];
      float2 p0 = t2[(size_t)i0*64];
      float2 p1 = t2[(size_t)i1*64];
      float2 p2 = t2[(size_t)i2*64];
      float2 p3 = t2[(size_t)i3*64];
      float2 p4 = t2[(size_t)i4*64];
      float w0 = sc2[l+0], w1 = sc2[l+1], w2 = sc2[l+2], w3 = sc2[l+3], w4 = sc2[l+4];
      gx = fmaf(w0, p0.x, gx); gy = fmaf(w0, p0.y, gy);
      gx = fmaf(w1, p1.x, gx); gy = fmaf(w1, p1.y, gy);
      gx = fmaf(w2, p2.x, gx); gy = fmaf(w2, p2.y, gy);
      gx = fmaf(w3, p3.x, gx); gy = fmaf(w3, p3.y, gy);
      gx = fmaf(w4, p4.x, gx); gy = fmaf(w4, p4.y, gy);
    }
    sg3[2*lane] = gx; sg3[2*lane+1] = gy;
  }
  __syncthreads();
  if (d < 50){
    float s = 0.f;
    for (int k = 0; k < 128; ++k) s = fmaf(sg2[k], weight[k*50 + d], s);
    s += c1b[0];
    ssel[d] = s;
    out[(size_t)Bn + (size_t)b*100 + d] = s;
  } else if (d >= 64 && d < 114){
    int t = d - 64;
    float s = 0.f;
    for (int k = 0; k < 128; ++k) s = fmaf(sg3[k], weight2[k*50 + t], s);
    s += c2b[0];
    ssel[50 + t] = s;
    out[(size_t)Bn + (size_t)b*100 + 50 + t] = s;
  }
  __syncthreads();
  if (d < 5){
    float s = clsb[d];
    for (int j = 0; j < 100; ++j) s = fmaf(ssel[j], cls[j*5 + d], s);
    spre[d] = s;
  }
  __syncthreads();
  if (d == 0){
    int best = 0; float bv = spre[0];
    #pragma unroll
    for (int k = 1; k < 5; ++k) if (spre[k] > bv){ bv = spre[k]; best = k; }
    out[b] = (float)best;
  }
}

// ---------------------------------------------------------------------------
extern "C" void kernel_launch(void* const* d_in, const int* in_sizes, int n_in,
                              void* d_out, int out_size, void* d_ws, size_t ws_size,
                              hipStream_t stream) {
  const float* A1     = (const float*)d_in[0];
  const int*   rows   = (const int*)  d_in[1];
  const int*   cols   = (const int*)  d_in[2];
  const float* vals   = (const float*)d_in[3];
  const int*   bidx   = (const int*)  d_in[4];
  const float* raw_c  = (const float*)d_in[5];
  const float* nparam = (const float*)d_in[6];
  const float* Lin1   = (const float*)d_in[7];
  const float* Lin1_b = (const float*)d_in[8];
  const float* gc1_w  = (const float*)d_in[9];
  const float* gc1_b  = (const float*)d_in[10];
  const float* gc2_w  = (const float*)d_in[11];
  const float* gc2_b  = (const float*)d_in[12];
  const float* weight = (const float*)d_in[13];
  const float* weight2= (const float*)d_in[14];
  const float* c1w    = (const float*)d_in[15];
  const float* c1b    = (const float*)d_in[16];
  const float* c2w    = (const float*)d_in[17];
  const float* c2b    = (const float*)d_in[18];
  const float* cls    = (const float*)d_in[19];
  const float* clsb   = (const float*)d_in[20];

  int N  = in_sizes[0] / 129;
  int E  = in_sizes[1];
  int Bn = in_sizes[4] / 50;
  size_t NF = (size_t)N * 128;

  // workspace layout (round-2: Lhi/Llo early, reused as packed Lx2 late)
  ushort_t* Lhi = (ushort_t*)d_ws;              // 2NF B
  ushort_t* Llo = Lhi + NF;                     // 2NF B
  unsigned int* Lx2p = (unsigned int*)d_ws;     // Lx2 packed bf16 (aliases Lhi/Llo)
  float*    S3  = (float*)(Llo + NF);           // loga1 fp32, 4NF B
  unsigned int* Hb   = (unsigned int*)(S3 + NF);  // h1/h2 bf16, NF/2 uints
  unsigned int* X1hi = Hb + NF/2;               // Lx1 hi
  unsigned int* X1lo = X1hi + NF/2;             // Lx1 lo
  ushort_t* Wb = (ushort_t*)(X1lo + NF/2);      // 6 x 16384 ushorts
  ushort_t* W1h = Wb,           *W1l = Wb + 16384;
  ushort_t* W2h = Wb + 2*16384, *W2l = Wb + 3*16384;
  ushort_t* W3h = Wb + 4*16384, *W3l = Wb + 5*16384;
  int* cnt    = (int*)(Wb + 6*16384);
  int* off    = cnt + N;
  int* rnk    = off + N;
  int* bsum   = rnk + E;
  int2* ecv   = (int2*)(bsum + 4096);
  float* uu3  = (float*)(ecv + E);

  int rowBlocks  = (N + 3) / 4;
  int G = (N + 256*SCAN_ITEMS - 1) / (256*SCAN_ITEMS);
  int histB = (E/4 + 255) / 256 + 1;
  int sBlocks = (int)(((size_t)N*32 + 255)/256);
  int mBlocks = 512;                 // 2 blocks/CU (64 KB LDS each)
  int nWaves  = mBlocks * 4;

  // cnt must be zero before any hist atomic (prep runs hist blocks first)
  hipMemsetAsync(cnt, 0, (size_t)N*sizeof(int), stream);
  prep<<<histB + sBlocks + 192, 256, 0, stream>>>(rows, cnt, rnk, E,
                                                  A1, Lhi, Llo,
                                                  Lin1, gc1_w, gc2_w, Wb,
                                                  Lin1_b, gc1_b, gc2_b, uu3,
                                                  N, histB, sBlocks);
  scan1<<<G, 256, 0, stream>>>(cnt, off, bsum, N);
  scan2<<<1, 256, 0, stream>>>(bsum, G);
  fill_k<<<histB, 256, 0, stream>>>(rows, cols, vals, off, bsum, rnk, ecv, E);

  // loga1 = chain(L@Lin1[1:,:], lin1_b) -> S3 (fp32)
  mfma_chain<<<mBlocks, 256, 0, stream>>>(Lhi, Llo, W1h, W1l, Lin1_b, uu3, 0, raw_c,
                                          S3, (unsigned int*)nullptr, 0, N, nWaves);
  // h1 = chain(L@gc1_w[1:,:], gc1_b) -> Hb (bf16)
  mfma_chain<<<mBlocks, 256, 0, stream>>>(Lhi, Llo, W2h, W2l, gc1_b, uu3, 1, raw_c,
                                          (float*)nullptr, Hb, 1, N, nWaves);
  seg_x1<<<rowBlocks, 256, 0, stream>>>(Hb, off, bsum, cnt, ecv, S3, nparam,
                                        X1hi, X1lo, N);
  // h2 = chain(Lx1@gc2_w, gc2_b) -> Hb (bf16)
  mfma_chain<<<mBlocks, 256, 0, stream>>>((const ushort_t*)X1hi, (const ushort_t*)X1lo,
                                          W3h, W3l, gc2_b, uu3, 2, raw_c,
                                          (float*)nullptr, Hb, 1, N, nWaves);
  seg_x2<<<rowBlocks, 256, 0, stream>>>(Hb, off, bsum, cnt, ecv, Lx2p, N);
  batch_head<<<Bn, 128, 0, stream>>>(Lx2p, S3, bidx, weight, weight2, c1w, c1b,
                                     c2w, c2b, cls, clsb, (float*)d_out, Bn);
}